// Round 15
// baseline (281.959 us; speedup 1.0000x reference)
//
#include <hip/hip_runtime.h>
#include <math.h>

#define N_NODES 40000
#define N_EDGES 640000
#define IN_DIM 128
#define EDGE_DIM 64
#define HID 128

typedef __attribute__((ext_vector_type(8))) short bf16x8;
typedef __attribute__((ext_vector_type(4))) float f32x4;

__device__ __forceinline__ ushort f2bf(float f) {
    unsigned int x = __float_as_uint(f);
    x += 0x7fffu + ((x >> 16) & 1u);
    return (ushort)(x >> 16);
}
__device__ __forceinline__ float bf2f(ushort u) {
    return __uint_as_float(((unsigned int)u) << 16);
}
// tanh(x) = 1 - 2/(e^{2x}+1); e^{2x}=inf -> 1, e^{2x}=0 -> -1 (no NaN)
__device__ __forceinline__ float tanh_fast(float x) {
    return 1.f - __fdividef(2.f, __expf(2.f * x) + 1.f);
}

// ---------------------------------------------------------------------------
// Setup A: W_comb = W_edge @ W1[256:384]; b_eff = b_att1 + b_edge @ W1he
// ---------------------------------------------------------------------------
__global__ __launch_bounds__(256) void k_wcomb(
    const float* __restrict__ W_edge, const float* __restrict__ W1,
    const float* __restrict__ b_att1, const float* __restrict__ b_edge,
    float* __restrict__ Wc, float* __restrict__ b_eff)
{
    const float* W1he = W1 + 256 * 128;
    if (blockIdx.x == 32) {
        const int n = threadIdx.x;
        if (n < 128) {
            float s = b_att1[n];
            for (int k = 0; k < 128; ++k) s = fmaf(b_edge[k], W1he[k * 128 + n], s);
            b_eff[n] = s;
        }
        return;
    }
    const int idx = blockIdx.x * 256 + threadIdx.x;
    const int row = idx >> 7, n = idx & 127;
    float s = 0.f;
    for (int k = 0; k < 128; ++k) s = fmaf(W_edge[row * 128 + k], W1he[k * 128 + n], s);
    Wc[idx] = s;
}

// ---------------------------------------------------------------------------
// Setup B: pack all weight fragments, bf16.
//  idx<32768          : packB  (B-op, W1 rows 0..255, G1/G2 GEMMs)
//  32768..40959       : packA  (A-op, Wc^T, edge GEMM)
//  40960..57343       : packN  (B-op, W_node)
//  57344..73727       : packO  (B-op, W_out)
// ---------------------------------------------------------------------------
__global__ __launch_bounds__(256) void k_pack(
    const float* __restrict__ W1, const float* __restrict__ Wc,
    const float* __restrict__ Wn, const float* __restrict__ Wo,
    ushort* __restrict__ packB, ushort* __restrict__ packA,
    ushort* __restrict__ packN, ushort* __restrict__ packO)
{
    const int idx = blockIdx.x * 256 + threadIdx.x;   // 0..73727
    if (idx < 32768) {
        const int j = idx & 7, lane = (idx >> 3) & 63, nt = (idx >> 9) & 7, k0 = idx >> 12;
        const int k = k0 * 32 + (lane >> 4) * 8 + j;
        const int n = nt * 16 + (lane & 15);
        packB[idx] = f2bf(W1[k * 128 + n]);
    } else if (idx < 40960) {
        const int i2 = idx - 32768;
        const int j = i2 & 7, lane = (i2 >> 3) & 63, mt = (i2 >> 9) & 7, k0 = i2 >> 12;
        const int k = k0 * 32 + (lane >> 4) * 8 + j;
        const int row = mt * 16 + (lane & 15);
        packA[i2] = f2bf(Wc[k * 128 + row]);
    } else if (idx < 57344) {
        const int i3 = idx - 40960;
        const int j = i3 & 7, lane = (i3 >> 3) & 63, nt = (i3 >> 9) & 7, k0 = i3 >> 12;
        const int k = k0 * 32 + (lane >> 4) * 8 + j;
        const int n = nt * 16 + (lane & 15);
        packN[i3] = f2bf(Wn[k * 128 + n]);
    } else {
        const int i4 = idx - 57344;
        const int j = i4 & 7, lane = (i4 >> 3) & 63, nt = (i4 >> 9) & 7, k0 = i4 >> 12;
        const int k = k0 * 32 + (lane >> 4) * 8 + j;
        const int n = nt * 16 + (lane & 15);
        packO[i4] = f2bf(Wo[k * 128 + n]);
    }
}

// ---------------------------------------------------------------------------
// K1: h = X @ W_node + b_node via MFMA (X fp32 -> bf16 on the fly); Hb bf16.
// ---------------------------------------------------------------------------
__global__ __launch_bounds__(256) void k_node_gemm(
    const float* __restrict__ X, const ushort* __restrict__ packN,
    const float* __restrict__ b, ushort* __restrict__ Hb)
{
    const int tid = threadIdx.x;
    const int wave = tid >> 6, lane = tid & 63;
    const int r = lane & 15, g = lane >> 4;
    const int nbase = blockIdx.x * 64 + wave * 16;
    const float* rowX = X + (size_t)(nbase + r) * 128 + g * 8;
    const bf16x8* Bp = reinterpret_cast<const bf16x8*>(packN);

    f32x4 acc[8];
#pragma unroll
    for (int nt = 0; nt < 8; ++nt) {
        const float bv = b[nt * 16 + r];
        acc[nt] = (f32x4){bv, bv, bv, bv};
    }
#pragma unroll
    for (int k0 = 0; k0 < 4; ++k0) {
        const float4 u0 = *reinterpret_cast<const float4*>(rowX + k0 * 32);
        const float4 u1 = *reinterpret_cast<const float4*>(rowX + k0 * 32 + 4);
        bf16x8 a;
        a[0] = (short)f2bf(u0.x); a[1] = (short)f2bf(u0.y);
        a[2] = (short)f2bf(u0.z); a[3] = (short)f2bf(u0.w);
        a[4] = (short)f2bf(u1.x); a[5] = (short)f2bf(u1.y);
        a[6] = (short)f2bf(u1.z); a[7] = (short)f2bf(u1.w);
#pragma unroll
        for (int nt = 0; nt < 8; ++nt)
            acc[nt] = __builtin_amdgcn_mfma_f32_16x16x32_bf16(
                a, Bp[(k0 * 8 + nt) * 64 + lane], acc[nt], 0, 0, 0);
    }
#pragma unroll
    for (int nt = 0; nt < 8; ++nt) {
#pragma unroll
        for (int q = 0; q < 4; ++q)
            Hb[(size_t)(nbase + g * 4 + q) * 128 + nt * 16 + r] = f2bf(acc[nt][q]);
    }
}

// ---------------------------------------------------------------------------
// K1b: G1 = Hb @ W1a + b_eff ; G2 = Hb @ W1b   (both [N,128] bf16)
// ---------------------------------------------------------------------------
__global__ __launch_bounds__(256) void k_node_g12(
    const ushort* __restrict__ Hb, const ushort* __restrict__ packB,
    const float* __restrict__ b_eff,
    ushort* __restrict__ G1, ushort* __restrict__ G2)
{
    const int tid = threadIdx.x;
    const int wave = tid >> 6, lane = tid & 63;
    const int r = lane & 15, g = lane >> 4;
    const int nbase = blockIdx.x * 64 + wave * 16;
    const ushort* rowA = Hb + (size_t)(nbase + r) * 128 + g * 8;
    const bf16x8* Bp = reinterpret_cast<const bf16x8*>(packB);

    f32x4 acc[8];
#pragma unroll
    for (int nt = 0; nt < 8; ++nt) acc[nt] = (f32x4){0.f, 0.f, 0.f, 0.f};
#pragma unroll
    for (int k0 = 0; k0 < 4; ++k0) {
        const bf16x8 a = *reinterpret_cast<const bf16x8*>(rowA + k0 * 32);
#pragma unroll
        for (int nt = 0; nt < 8; ++nt)
            acc[nt] = __builtin_amdgcn_mfma_f32_16x16x32_bf16(
                a, Bp[(k0 * 8 + nt) * 64 + lane], acc[nt], 0, 0, 0);
    }
#pragma unroll
    for (int nt = 0; nt < 8; ++nt) {
        const float bv = b_eff[nt * 16 + r];
#pragma unroll
        for (int q = 0; q < 4; ++q)
            G1[(size_t)(nbase + g * 4 + q) * 128 + nt * 16 + r] = f2bf(acc[nt][q] + bv);
    }

#pragma unroll
    for (int nt = 0; nt < 8; ++nt) acc[nt] = (f32x4){0.f, 0.f, 0.f, 0.f};
#pragma unroll
    for (int k0 = 0; k0 < 4; ++k0) {
        const bf16x8 a = *reinterpret_cast<const bf16x8*>(rowA + k0 * 32);
#pragma unroll
        for (int nt = 0; nt < 8; ++nt)
            acc[nt] = __builtin_amdgcn_mfma_f32_16x16x32_bf16(
                a, Bp[((k0 + 4) * 8 + nt) * 64 + lane], acc[nt], 0, 0, 0);
    }
#pragma unroll
    for (int nt = 0; nt < 8; ++nt) {
#pragma unroll
        for (int q = 0; q < 4; ++q)
            G2[(size_t)(nbase + g * 4 + q) * 128 + nt * 16 + r] = f2bf(acc[nt][q]);
    }
}

// ---------------------------------------------------------------------------
// CSR build: histogram -> single-block scan -> fill permutation (se,de,pe)
// ---------------------------------------------------------------------------
__global__ __launch_bounds__(256) void k_hist(
    const int* __restrict__ srcI, int* __restrict__ cnt)
{
    const int e = blockIdx.x * 256 + threadIdx.x;
    atomicAdd(&cnt[srcI[e]], 1);
}

__global__ __launch_bounds__(1024) void k_scan(
    const int* __restrict__ cnt, int* __restrict__ rowptr)
{
    __shared__ int wsum[16];
    __shared__ int carry;
    const int tid = threadIdx.x, lane = tid & 63, wid = tid >> 6;
    if (tid == 0) { carry = 0; rowptr[0] = 0; }
    __syncthreads();
    for (int base = 0; base < N_NODES; base += 4096) {
        const int i = base + tid * 4;
        int4 c = {0, 0, 0, 0};
        if (i < N_NODES) c = *reinterpret_cast<const int4*>(cnt + i);
        const int tsum = c.x + c.y + c.z + c.w;
        int v = tsum;
#pragma unroll
        for (int d = 1; d < 64; d <<= 1) {
            const int t = __shfl_up(v, d, 64);
            if (lane >= d) v += t;
        }
        if (lane == 63) wsum[wid] = v;
        __syncthreads();
        if (wid == 0 && lane < 16) {
            int w = wsum[lane];
#pragma unroll
            for (int d = 1; d < 16; d <<= 1) {
                const int t = __shfl_up(w, d, 16);
                if ((lane & 15) >= d) w += t;
            }
            wsum[lane] = w;
        }
        __syncthreads();
        const int off = (wid == 0) ? 0 : wsum[wid - 1];
        const int excl = carry + off + v - tsum;
        if (i < N_NODES) {
            rowptr[i + 1] = excl + c.x;
            rowptr[i + 2] = excl + c.x + c.y;
            rowptr[i + 3] = excl + c.x + c.y + c.z;
            rowptr[i + 4] = excl + tsum;
        }
        const int total = wsum[15];
        __syncthreads();
        if (tid == 0) carry += total;
        __syncthreads();
    }
}

__global__ __launch_bounds__(256) void k_fill(
    const int* __restrict__ srcI, const int* __restrict__ dstI,
    const int* __restrict__ rowptr, int* __restrict__ cursor,
    int* __restrict__ se, int* __restrict__ de, int* __restrict__ pe)
{
    const int e = blockIdx.x * 256 + threadIdx.x;
    const int s = srcI[e];
    const int pos = rowptr[s] + atomicAdd(&cursor[s], 1);
    se[pos] = s;
    de[pos] = dstI[e];
    pe[pos] = e;
}

// ---------------------------------------------------------------------------
// K2 v6: CSR-ordered edge attention. Wave = 16 consecutive CSR slots
// (avg degree 16 -> G1[src] rows are L1-hot). No atomics; coalesced
// csr_p[pos] store. z^T = Wc^T@EF[pe[pos]]^T (MFMA) + G1[se] + G2[de];
// tanh; dot W2; exp. Only G2 (random) is register-hoisted.
// ---------------------------------------------------------------------------
__global__ __launch_bounds__(256) void k_edge_att_v6(
    const int* __restrict__ se, const int* __restrict__ de,
    const int* __restrict__ pe, const float* __restrict__ EF,
    const ushort* __restrict__ G1, const ushort* __restrict__ G2,
    const ushort* __restrict__ packA,
    const float* __restrict__ W2, const float* __restrict__ b2,
    float* __restrict__ csr_p)
{
    const int tid = threadIdx.x;
    const int wave = tid >> 6, lane = tid & 63;
    const int r = lane & 15, g = lane >> 4;
    const int pbase = blockIdx.x * 64 + wave * 16;
    const int pos = pbase + r;
    const int si = se[pos], di = de[pos], e = pe[pos];

    // hoisted gather: G2[dst] (random rows) in accumulator layout
    const ushort* g2row = G2 + (size_t)di * 128 + g * 4;
    ushort4 g2v[8];
#pragma unroll
    for (int mt = 0; mt < 8; ++mt)
        g2v[mt] = *reinterpret_cast<const ushort4*>(g2row + mt * 16);

    // B-frags: EF[e][32*k0 + 8g + j], fp32 -> bf16
    const float* rowE = EF + (size_t)e * 64 + g * 8;
    bf16x8 b0, b1;
    {
        const float4 u0 = *reinterpret_cast<const float4*>(rowE);
        const float4 u1 = *reinterpret_cast<const float4*>(rowE + 4);
        b0[0] = (short)f2bf(u0.x); b0[1] = (short)f2bf(u0.y);
        b0[2] = (short)f2bf(u0.z); b0[3] = (short)f2bf(u0.w);
        b0[4] = (short)f2bf(u1.x); b0[5] = (short)f2bf(u1.y);
        b0[6] = (short)f2bf(u1.z); b0[7] = (short)f2bf(u1.w);
        const float4 v0 = *reinterpret_cast<const float4*>(rowE + 32);
        const float4 v1 = *reinterpret_cast<const float4*>(rowE + 36);
        b1[0] = (short)f2bf(v0.x); b1[1] = (short)f2bf(v0.y);
        b1[2] = (short)f2bf(v0.z); b1[3] = (short)f2bf(v0.w);
        b1[4] = (short)f2bf(v1.x); b1[5] = (short)f2bf(v1.y);
        b1[6] = (short)f2bf(v1.z); b1[7] = (short)f2bf(v1.w);
    }

    const bf16x8* Ap = reinterpret_cast<const bf16x8*>(packA);  // 16 KB, L2-hot
    f32x4 acc[8];
#pragma unroll
    for (int mt = 0; mt < 8; ++mt) acc[mt] = (f32x4){0.f, 0.f, 0.f, 0.f};
#pragma unroll
    for (int mt = 0; mt < 8; ++mt)
        acc[mt] = __builtin_amdgcn_mfma_f32_16x16x32_bf16(
            Ap[(0 * 8 + mt) * 64 + lane], b0, acc[mt], 0, 0, 0);
#pragma unroll
    for (int mt = 0; mt < 8; ++mt)
        acc[mt] = __builtin_amdgcn_mfma_f32_16x16x32_bf16(
            Ap[(1 * 8 + mt) * 64 + lane], b1, acc[mt], 0, 0, 0);

    // z += G1[src] (L1-hot, loaded late) + G2 ; a = sum tanh(z)*W2
    const ushort* g1row = G1 + (size_t)si * 128 + g * 4;
    float part = 0.f;
#pragma unroll
    for (int mt = 0; mt < 8; ++mt) {
        const ushort4 g1v = *reinterpret_cast<const ushort4*>(g1row + mt * 16);
        const float4 w2v = *reinterpret_cast<const float4*>(W2 + mt * 16 + g * 4);
        const float z0 = acc[mt][0] + bf2f(g1v.x) + bf2f(g2v[mt].x);
        const float z1 = acc[mt][1] + bf2f(g1v.y) + bf2f(g2v[mt].y);
        const float z2 = acc[mt][2] + bf2f(g1v.z) + bf2f(g2v[mt].z);
        const float z3 = acc[mt][3] + bf2f(g1v.w) + bf2f(g2v[mt].w);
        part = fmaf(tanh_fast(z0), w2v.x, part);
        part = fmaf(tanh_fast(z1), w2v.y, part);
        part = fmaf(tanh_fast(z2), w2v.z, part);
        part = fmaf(tanh_fast(z3), w2v.w, part);
    }
    part += __shfl_xor(part, 16, 64);
    part += __shfl_xor(part, 32, 64);
    if (lane < 16) csr_p[pos] = __expf(part + b2[0]);
}

// ---------------------------------------------------------------------------
// K3: per-node gather-aggregate, wave-per-node; (csr_p, de) streams; bf16 out.
// ---------------------------------------------------------------------------
__global__ __launch_bounds__(256) void k_agg(
    const int* __restrict__ rowptr, const float* __restrict__ csr_p,
    const int* __restrict__ de, const ushort* __restrict__ Hb,
    ushort* __restrict__ AGGb)
{
    const int tid = threadIdx.x;
    const int wave = tid >> 6, lane = tid & 63;
    const int slot = lane >> 5, tc = lane & 31;
    const int n = blockIdx.x * 4 + wave;
    const int beg = rowptr[n], end = rowptr[n + 1];

    float4 v = {0.f, 0.f, 0.f, 0.f};
    float sp = 0.f;
    for (int j = beg + slot; j < end; j += 2) {
        const float p = csr_p[j];
        const int d = de[j];
        const ushort4 hv = *reinterpret_cast<const ushort4*>(Hb + (size_t)d * 128 + tc * 4);
        v.x = fmaf(p, bf2f(hv.x), v.x);
        v.y = fmaf(p, bf2f(hv.y), v.y);
        v.z = fmaf(p, bf2f(hv.z), v.z);
        v.w = fmaf(p, bf2f(hv.w), v.w);
        sp += p;
    }
    v.x += __shfl_xor(v.x, 32, 64);
    v.y += __shfl_xor(v.y, 32, 64);
    v.z += __shfl_xor(v.z, 32, 64);
    v.w += __shfl_xor(v.w, 32, 64);
    sp  += __shfl_xor(sp, 32, 64);
    if (lane < 32) {
        const float inv = (end > beg) ? 1.f / sp : 0.f;
        ushort4 o;
        o.x = f2bf(v.x * inv); o.y = f2bf(v.y * inv);
        o.z = f2bf(v.z * inv); o.w = f2bf(v.w * inv);
        *reinterpret_cast<ushort4*>(AGGb + (size_t)n * 128 + lane * 4) = o;
    }
}

// ---------------------------------------------------------------------------
// K4: o = agg @ W_out + b_out (MFMA) ; LayerNorm ; ReLU
// ---------------------------------------------------------------------------
__global__ __launch_bounds__(256) void k_out_ln(
    const ushort* __restrict__ AGGb, const ushort* __restrict__ packO,
    const float* __restrict__ b, const float* __restrict__ gamma,
    const float* __restrict__ beta, float* __restrict__ OUT)
{
    const int tid = threadIdx.x;
    const int wave = tid >> 6, lane = tid & 63;
    const int r = lane & 15, g = lane >> 4;
    const int nbase = blockIdx.x * 64 + wave * 16;
    const ushort* rowA = AGGb + (size_t)(nbase + r) * 128 + g * 8;
    const bf16x8* Bp = reinterpret_cast<const bf16x8*>(packO);

    f32x4 acc[8];
#pragma unroll
    for (int nt = 0; nt < 8; ++nt) {
        const float bv = b[nt * 16 + r];
        acc[nt] = (f32x4){bv, bv, bv, bv};
    }
#pragma unroll
    for (int k0 = 0; k0 < 4; ++k0) {
        const bf16x8 a = *reinterpret_cast<const bf16x8*>(rowA + k0 * 32);
#pragma unroll
        for (int nt = 0; nt < 8; ++nt)
            acc[nt] = __builtin_amdgcn_mfma_f32_16x16x32_bf16(
                a, Bp[(k0 * 8 + nt) * 64 + lane], acc[nt], 0, 0, 0);
    }

    float s1[4] = {0.f, 0.f, 0.f, 0.f};
    float s2[4] = {0.f, 0.f, 0.f, 0.f};
#pragma unroll
    for (int nt = 0; nt < 8; ++nt) {
#pragma unroll
        for (int q = 0; q < 4; ++q) {
            const float z = acc[nt][q];
            s1[q] += z;
            s2[q] = fmaf(z, z, s2[q]);
        }
    }
#pragma unroll
    for (int m = 1; m <= 8; m <<= 1) {
#pragma unroll
        for (int q = 0; q < 4; ++q) {
            s1[q] += __shfl_xor(s1[q], m, 64);
            s2[q] += __shfl_xor(s2[q], m, 64);
        }
    }
    float mu[4], rr[4];
#pragma unroll
    for (int q = 0; q < 4; ++q) {
        mu[q] = s1[q] * (1.f / 128.f);
        const float var = s2[q] * (1.f / 128.f) - mu[q] * mu[q];
        rr[q] = rsqrtf(var + 1e-5f);
    }
#pragma unroll
    for (int nt = 0; nt < 8; ++nt) {
        const int col = nt * 16 + r;
        const float ga = gamma[col], be = beta[col];
#pragma unroll
        for (int q = 0; q < 4; ++q) {
            const float o = (acc[nt][q] - mu[q]) * rr[q] * ga + be;
            OUT[(size_t)(nbase + g * 4 + q) * 128 + col] = o > 0.f ? o : 0.f;
        }
    }
}

// ---------------------------------------------------------------------------
extern "C" void kernel_launch(void* const* d_in, const int* in_sizes, int n_in,
                              void* d_out, int out_size, void* d_ws, size_t ws_size,
                              hipStream_t stream)
{
    const float* node_features = (const float*)d_in[0];
    const int*   edge_index    = (const int*)d_in[1];
    const float* edge_features = (const float*)d_in[2];
    const float* W_node  = (const float*)d_in[3];
    const float* b_node  = (const float*)d_in[4];
    const float* W_edge  = (const float*)d_in[5];
    const float* b_edge  = (const float*)d_in[6];
    const float* W_att1  = (const float*)d_in[7];
    const float* b_att1  = (const float*)d_in[8];
    const float* W_att2  = (const float*)d_in[9];
    const float* b_att2  = (const float*)d_in[10];
    const float* W_out   = (const float*)d_in[11];
    const float* b_out   = (const float*)d_in[12];
    const float* ln_gamma = (const float*)d_in[13];
    const float* ln_beta  = (const float*)d_in[14];
    float* out = (float*)d_out;

    // workspace layout (byte offsets, 16B-aligned).
    // se/pe alias the aggb region: they are dead before k_agg writes aggb.
    char* ws = (char*)d_ws;
    ushort* hb      = (ushort*)(ws);                   // 10,240,000 B
    ushort* G1      = (ushort*)(ws + 10240000);        // 10,240,000 B
    ushort* G2      = (ushort*)(ws + 20480000);        // 10,240,000 B
    ushort* aggb    = (ushort*)(ws + 30720000);        // 10,240,000 B
    int*    se      = (int*)(ws + 30720000);           //  2,560,000 B (alias aggb)
    int*    pe      = (int*)(ws + 33280000);           //  2,560,000 B (alias aggb)
    float*  csr_p   = (float*)(ws + 40960000);         //  2,560,000 B
    int*    de      = (int*)(ws + 43520000);           //  2,560,000 B
    int*    rowptr  = (int*)(ws + 46080000);           //    160,004 B
    int*    cnt     = (int*)(ws + 46240016);           //    160,000 B
    int*    cursor  = (int*)(ws + 46400016);           //    160,000 B (contiguous after cnt)
    float*  Wc      = (float*)(ws + 46560016);         //     32,768 B
    float*  b_eff   = (float*)(ws + 46592784);         //        512 B
    ushort* packB   = (ushort*)(ws + 46593296);        //     65,536 B
    ushort* packA   = (ushort*)(ws + 46658832);        //     16,384 B
    ushort* packN   = (ushort*)(ws + 46675216);        //     32,768 B
    ushort* packO   = (ushort*)(ws + 46707984);        //     32,768 B

    const int* srcI = edge_index;
    const int* dstI = edge_index + N_EDGES;

    // zero histogram + fill cursors (contiguous)
    hipMemsetAsync(cnt, 0, 320000, stream);

    k_wcomb<<<33, 256, 0, stream>>>(W_edge, W_att1, b_att1, b_edge, Wc, b_eff);
    k_pack<<<288, 256, 0, stream>>>(W_att1, Wc, W_node, W_out,
                                    packB, packA, packN, packO);
    k_node_gemm<<<N_NODES / 64, 256, 0, stream>>>(node_features, packN, b_node, hb);
    k_node_g12<<<N_NODES / 64, 256, 0, stream>>>(hb, packB, b_eff, G1, G2);
    k_hist<<<N_EDGES / 256, 256, 0, stream>>>(srcI, cnt);
    k_scan<<<1, 1024, 0, stream>>>(cnt, rowptr);
    k_fill<<<N_EDGES / 256, 256, 0, stream>>>(srcI, dstI, rowptr, cursor, se, de, pe);
    k_edge_att_v6<<<N_EDGES / 64, 256, 0, stream>>>(se, de, pe, edge_features,
                                                    G1, G2, packA, W_att2, b_att2,
                                                    csr_p);
    k_agg<<<N_NODES / 4, 256, 0, stream>>>(rowptr, csr_p, de, hb, aggb);
    k_out_ln<<<N_NODES / 64, 256, 0, stream>>>(aggb, packO, b_out, ln_gamma, ln_beta, out);
}

// Round 16
// 261.322 us; speedup vs baseline: 1.0790x; 1.0790x over previous
//
#include <hip/hip_runtime.h>
#include <math.h>

#define N_NODES 40000
#define N_EDGES 640000
#define IN_DIM 128
#define EDGE_DIM 64
#define HID 128

typedef __attribute__((ext_vector_type(8))) short bf16x8;
typedef __attribute__((ext_vector_type(4))) float f32x4;

__device__ __forceinline__ ushort f2bf(float f) {
    unsigned int x = __float_as_uint(f);
    x += 0x7fffu + ((x >> 16) & 1u);
    return (ushort)(x >> 16);
}
__device__ __forceinline__ float bf2f(ushort u) {
    return __uint_as_float(((unsigned int)u) << 16);
}
// tanh(x) = 1 - 2/(e^{2x}+1); e^{2x}=inf -> 1, e^{2x}=0 -> -1 (no NaN)
__device__ __forceinline__ float tanh_fast(float x) {
    return 1.f - __fdividef(2.f, __expf(2.f * x) + 1.f);
}

// ---------------------------------------------------------------------------
// Setup A: W_comb = W_edge @ W1[256:384]; b_eff = b_att1 + b_edge @ W1he
// ---------------------------------------------------------------------------
__global__ __launch_bounds__(256) void k_wcomb(
    const float* __restrict__ W_edge, const float* __restrict__ W1,
    const float* __restrict__ b_att1, const float* __restrict__ b_edge,
    float* __restrict__ Wc, float* __restrict__ b_eff)
{
    const float* W1he = W1 + 256 * 128;
    if (blockIdx.x == 32) {
        const int n = threadIdx.x;
        if (n < 128) {
            float s = b_att1[n];
            for (int k = 0; k < 128; ++k) s = fmaf(b_edge[k], W1he[k * 128 + n], s);
            b_eff[n] = s;
        }
        return;
    }
    const int idx = blockIdx.x * 256 + threadIdx.x;
    const int row = idx >> 7, n = idx & 127;
    float s = 0.f;
    for (int k = 0; k < 128; ++k) s = fmaf(W_edge[row * 128 + k], W1he[k * 128 + n], s);
    Wc[idx] = s;
}

// ---------------------------------------------------------------------------
// Setup B: pack all weight fragments, bf16.
//  idx<32768          : packB  (B-op, W1 rows 0..255, G1/G2 GEMMs)
//  32768..40959       : packA  (A-op, Wc^T, edge GEMM)
//  40960..57343       : packN  (B-op, W_node)
//  57344..73727       : packO  (B-op, W_out)
// ---------------------------------------------------------------------------
__global__ __launch_bounds__(256) void k_pack(
    const float* __restrict__ W1, const float* __restrict__ Wc,
    const float* __restrict__ Wn, const float* __restrict__ Wo,
    ushort* __restrict__ packB, ushort* __restrict__ packA,
    ushort* __restrict__ packN, ushort* __restrict__ packO)
{
    const int idx = blockIdx.x * 256 + threadIdx.x;   // 0..73727
    if (idx < 32768) {
        const int j = idx & 7, lane = (idx >> 3) & 63, nt = (idx >> 9) & 7, k0 = idx >> 12;
        const int k = k0 * 32 + (lane >> 4) * 8 + j;
        const int n = nt * 16 + (lane & 15);
        packB[idx] = f2bf(W1[k * 128 + n]);
    } else if (idx < 40960) {
        const int i2 = idx - 32768;
        const int j = i2 & 7, lane = (i2 >> 3) & 63, mt = (i2 >> 9) & 7, k0 = i2 >> 12;
        const int k = k0 * 32 + (lane >> 4) * 8 + j;
        const int row = mt * 16 + (lane & 15);
        packA[i2] = f2bf(Wc[k * 128 + row]);
    } else if (idx < 57344) {
        const int i3 = idx - 40960;
        const int j = i3 & 7, lane = (i3 >> 3) & 63, nt = (i3 >> 9) & 7, k0 = i3 >> 12;
        const int k = k0 * 32 + (lane >> 4) * 8 + j;
        const int n = nt * 16 + (lane & 15);
        packN[i3] = f2bf(Wn[k * 128 + n]);
    } else {
        const int i4 = idx - 57344;
        const int j = i4 & 7, lane = (i4 >> 3) & 63, nt = (i4 >> 9) & 7, k0 = i4 >> 12;
        const int k = k0 * 32 + (lane >> 4) * 8 + j;
        const int n = nt * 16 + (lane & 15);
        packO[i4] = f2bf(Wo[k * 128 + n]);
    }
}

// ---------------------------------------------------------------------------
// K1: h = X @ W_node + b_node via MFMA (X fp32 -> bf16 on the fly); Hb bf16.
// ---------------------------------------------------------------------------
__global__ __launch_bounds__(256) void k_node_gemm(
    const float* __restrict__ X, const ushort* __restrict__ packN,
    const float* __restrict__ b, ushort* __restrict__ Hb)
{
    const int tid = threadIdx.x;
    const int wave = tid >> 6, lane = tid & 63;
    const int r = lane & 15, g = lane >> 4;
    const int nbase = blockIdx.x * 64 + wave * 16;
    const float* rowX = X + (size_t)(nbase + r) * 128 + g * 8;
    const bf16x8* Bp = reinterpret_cast<const bf16x8*>(packN);

    f32x4 acc[8];
#pragma unroll
    for (int nt = 0; nt < 8; ++nt) {
        const float bv = b[nt * 16 + r];
        acc[nt] = (f32x4){bv, bv, bv, bv};
    }
#pragma unroll
    for (int k0 = 0; k0 < 4; ++k0) {
        const float4 u0 = *reinterpret_cast<const float4*>(rowX + k0 * 32);
        const float4 u1 = *reinterpret_cast<const float4*>(rowX + k0 * 32 + 4);
        bf16x8 a;
        a[0] = (short)f2bf(u0.x); a[1] = (short)f2bf(u0.y);
        a[2] = (short)f2bf(u0.z); a[3] = (short)f2bf(u0.w);
        a[4] = (short)f2bf(u1.x); a[5] = (short)f2bf(u1.y);
        a[6] = (short)f2bf(u1.z); a[7] = (short)f2bf(u1.w);
#pragma unroll
        for (int nt = 0; nt < 8; ++nt)
            acc[nt] = __builtin_amdgcn_mfma_f32_16x16x32_bf16(
                a, Bp[(k0 * 8 + nt) * 64 + lane], acc[nt], 0, 0, 0);
    }
#pragma unroll
    for (int nt = 0; nt < 8; ++nt) {
#pragma unroll
        for (int q = 0; q < 4; ++q)
            Hb[(size_t)(nbase + g * 4 + q) * 128 + nt * 16 + r] = f2bf(acc[nt][q]);
    }
}

// ---------------------------------------------------------------------------
// K1b: G1 = Hb @ W1a + b_eff ; G2 = Hb @ W1b   (both [N,128] bf16)
// ---------------------------------------------------------------------------
__global__ __launch_bounds__(256) void k_node_g12(
    const ushort* __restrict__ Hb, const ushort* __restrict__ packB,
    const float* __restrict__ b_eff,
    ushort* __restrict__ G1, ushort* __restrict__ G2)
{
    const int tid = threadIdx.x;
    const int wave = tid >> 6, lane = tid & 63;
    const int r = lane & 15, g = lane >> 4;
    const int nbase = blockIdx.x * 64 + wave * 16;
    const ushort* rowA = Hb + (size_t)(nbase + r) * 128 + g * 8;
    const bf16x8* Bp = reinterpret_cast<const bf16x8*>(packB);

    f32x4 acc[8];
#pragma unroll
    for (int nt = 0; nt < 8; ++nt) acc[nt] = (f32x4){0.f, 0.f, 0.f, 0.f};
#pragma unroll
    for (int k0 = 0; k0 < 4; ++k0) {
        const bf16x8 a = *reinterpret_cast<const bf16x8*>(rowA + k0 * 32);
#pragma unroll
        for (int nt = 0; nt < 8; ++nt)
            acc[nt] = __builtin_amdgcn_mfma_f32_16x16x32_bf16(
                a, Bp[(k0 * 8 + nt) * 64 + lane], acc[nt], 0, 0, 0);
    }
#pragma unroll
    for (int nt = 0; nt < 8; ++nt) {
        const float bv = b_eff[nt * 16 + r];
#pragma unroll
        for (int q = 0; q < 4; ++q)
            G1[(size_t)(nbase + g * 4 + q) * 128 + nt * 16 + r] = f2bf(acc[nt][q] + bv);
    }

#pragma unroll
    for (int nt = 0; nt < 8; ++nt) acc[nt] = (f32x4){0.f, 0.f, 0.f, 0.f};
#pragma unroll
    for (int k0 = 0; k0 < 4; ++k0) {
        const bf16x8 a = *reinterpret_cast<const bf16x8*>(rowA + k0 * 32);
#pragma unroll
        for (int nt = 0; nt < 8; ++nt)
            acc[nt] = __builtin_amdgcn_mfma_f32_16x16x32_bf16(
                a, Bp[((k0 + 4) * 8 + nt) * 64 + lane], acc[nt], 0, 0, 0);
    }
#pragma unroll
    for (int nt = 0; nt < 8; ++nt) {
#pragma unroll
        for (int q = 0; q < 4; ++q)
            G2[(size_t)(nbase + g * 4 + q) * 128 + nt * 16 + r] = f2bf(acc[nt][q]);
    }
}

// ---------------------------------------------------------------------------
// CSR build: histogram -> single-block scan -> fill edrec = (e, dst) per slot
// ---------------------------------------------------------------------------
__global__ __launch_bounds__(256) void k_hist(
    const int* __restrict__ srcI, int* __restrict__ cnt)
{
    const int e = blockIdx.x * 256 + threadIdx.x;
    atomicAdd(&cnt[srcI[e]], 1);
}

__global__ __launch_bounds__(1024) void k_scan(
    const int* __restrict__ cnt, int* __restrict__ rowptr)
{
    __shared__ int wsum[16];
    __shared__ int carry;
    const int tid = threadIdx.x, lane = tid & 63, wid = tid >> 6;
    if (tid == 0) { carry = 0; rowptr[0] = 0; }
    __syncthreads();
    for (int base = 0; base < N_NODES; base += 4096) {
        const int i = base + tid * 4;
        int4 c = {0, 0, 0, 0};
        if (i < N_NODES) c = *reinterpret_cast<const int4*>(cnt + i);
        const int tsum = c.x + c.y + c.z + c.w;
        int v = tsum;
#pragma unroll
        for (int d = 1; d < 64; d <<= 1) {
            const int t = __shfl_up(v, d, 64);
            if (lane >= d) v += t;
        }
        if (lane == 63) wsum[wid] = v;
        __syncthreads();
        if (wid == 0 && lane < 16) {
            int w = wsum[lane];
#pragma unroll
            for (int d = 1; d < 16; d <<= 1) {
                const int t = __shfl_up(w, d, 16);
                if ((lane & 15) >= d) w += t;
            }
            wsum[lane] = w;
        }
        __syncthreads();
        const int off = (wid == 0) ? 0 : wsum[wid - 1];
        const int excl = carry + off + v - tsum;
        if (i < N_NODES) {
            rowptr[i + 1] = excl + c.x;
            rowptr[i + 2] = excl + c.x + c.y;
            rowptr[i + 3] = excl + c.x + c.y + c.z;
            rowptr[i + 4] = excl + tsum;
        }
        const int total = wsum[15];
        __syncthreads();
        if (tid == 0) carry += total;
        __syncthreads();
    }
}

__global__ __launch_bounds__(256) void k_fill(
    const int* __restrict__ srcI, const int* __restrict__ dstI,
    const int* __restrict__ rowptr, int* __restrict__ cursor,
    int2* __restrict__ edrec)
{
    const int e = blockIdx.x * 256 + threadIdx.x;
    const int s = srcI[e];
    const int pos = rowptr[s] + atomicAdd(&cursor[s], 1);
    int2 rec;
    rec.x = e;
    rec.y = dstI[e];
    edrec[pos] = rec;   // single 8B scattered store
}

// ---------------------------------------------------------------------------
// K2 v7: CSR-ordered edge attention. Wave = 16 consecutive CSR slots
// (avg degree 16 -> G1[src] rows L1-hot). si recovered via srcI[e] (L2-hot).
// z^T = Wc^T@EF[e]^T (MFMA) + G1[si] + G2[di]; tanh; dot W2; exp;
// coalesced csr_p[pos] store, no atomics.
// ---------------------------------------------------------------------------
__global__ __launch_bounds__(256) void k_edge_att_v7(
    const int2* __restrict__ edrec, const int* __restrict__ srcI,
    const float* __restrict__ EF,
    const ushort* __restrict__ G1, const ushort* __restrict__ G2,
    const ushort* __restrict__ packA,
    const float* __restrict__ W2, const float* __restrict__ b2,
    float* __restrict__ csr_p)
{
    const int tid = threadIdx.x;
    const int wave = tid >> 6, lane = tid & 63;
    const int r = lane & 15, g = lane >> 4;
    const int pbase = blockIdx.x * 64 + wave * 16;
    const int pos = pbase + r;
    const int2 rec = edrec[pos];
    const int e = rec.x, di = rec.y;
    const int si = srcI[e];

    // hoisted gather: G2[dst] (random rows) in accumulator layout
    const ushort* g2row = G2 + (size_t)di * 128 + g * 4;
    ushort4 g2v[8];
#pragma unroll
    for (int mt = 0; mt < 8; ++mt)
        g2v[mt] = *reinterpret_cast<const ushort4*>(g2row + mt * 16);

    // B-frags: EF[e][32*k0 + 8g + j], fp32 -> bf16
    const float* rowE = EF + (size_t)e * 64 + g * 8;
    bf16x8 b0, b1;
    {
        const float4 u0 = *reinterpret_cast<const float4*>(rowE);
        const float4 u1 = *reinterpret_cast<const float4*>(rowE + 4);
        b0[0] = (short)f2bf(u0.x); b0[1] = (short)f2bf(u0.y);
        b0[2] = (short)f2bf(u0.z); b0[3] = (short)f2bf(u0.w);
        b0[4] = (short)f2bf(u1.x); b0[5] = (short)f2bf(u1.y);
        b0[6] = (short)f2bf(u1.z); b0[7] = (short)f2bf(u1.w);
        const float4 v0 = *reinterpret_cast<const float4*>(rowE + 32);
        const float4 v1 = *reinterpret_cast<const float4*>(rowE + 36);
        b1[0] = (short)f2bf(v0.x); b1[1] = (short)f2bf(v0.y);
        b1[2] = (short)f2bf(v0.z); b1[3] = (short)f2bf(v0.w);
        b1[4] = (short)f2bf(v1.x); b1[5] = (short)f2bf(v1.y);
        b1[6] = (short)f2bf(v1.z); b1[7] = (short)f2bf(v1.w);
    }

    const bf16x8* Ap = reinterpret_cast<const bf16x8*>(packA);  // 16 KB, L2-hot
    f32x4 acc[8];
#pragma unroll
    for (int mt = 0; mt < 8; ++mt) acc[mt] = (f32x4){0.f, 0.f, 0.f, 0.f};
#pragma unroll
    for (int mt = 0; mt < 8; ++mt)
        acc[mt] = __builtin_amdgcn_mfma_f32_16x16x32_bf16(
            Ap[(0 * 8 + mt) * 64 + lane], b0, acc[mt], 0, 0, 0);
#pragma unroll
    for (int mt = 0; mt < 8; ++mt)
        acc[mt] = __builtin_amdgcn_mfma_f32_16x16x32_bf16(
            Ap[(1 * 8 + mt) * 64 + lane], b1, acc[mt], 0, 0, 0);

    // z += G1[src] (L1-hot, loaded late) + G2 ; a = sum tanh(z)*W2
    const ushort* g1row = G1 + (size_t)si * 128 + g * 4;
    float part = 0.f;
#pragma unroll
    for (int mt = 0; mt < 8; ++mt) {
        const ushort4 g1v = *reinterpret_cast<const ushort4*>(g1row + mt * 16);
        const float4 w2v = *reinterpret_cast<const float4*>(W2 + mt * 16 + g * 4);
        const float z0 = acc[mt][0] + bf2f(g1v.x) + bf2f(g2v[mt].x);
        const float z1 = acc[mt][1] + bf2f(g1v.y) + bf2f(g2v[mt].y);
        const float z2 = acc[mt][2] + bf2f(g1v.z) + bf2f(g2v[mt].z);
        const float z3 = acc[mt][3] + bf2f(g1v.w) + bf2f(g2v[mt].w);
        part = fmaf(tanh_fast(z0), w2v.x, part);
        part = fmaf(tanh_fast(z1), w2v.y, part);
        part = fmaf(tanh_fast(z2), w2v.z, part);
        part = fmaf(tanh_fast(z3), w2v.w, part);
    }
    part += __shfl_xor(part, 16, 64);
    part += __shfl_xor(part, 32, 64);
    if (lane < 16) csr_p[pos] = __expf(part + b2[0]);
}

// ---------------------------------------------------------------------------
// K3: per-node gather-aggregate, wave-per-node; 4 edge-slots x 16 col-lanes,
// 16B bf16x8 loads; (csr_p, edrec) streams; bf16 out.
// ---------------------------------------------------------------------------
__global__ __launch_bounds__(256) void k_agg(
    const int* __restrict__ rowptr, const float* __restrict__ csr_p,
    const int2* __restrict__ edrec, const ushort* __restrict__ Hb,
    ushort* __restrict__ AGGb)
{
    const int tid = threadIdx.x;
    const int wave = tid >> 6, lane = tid & 63;
    const int slot = lane >> 4, tc = lane & 15;
    const int n = blockIdx.x * 4 + wave;
    const int beg = rowptr[n], end = rowptr[n + 1];

    float v[8];
#pragma unroll
    for (int i = 0; i < 8; ++i) v[i] = 0.f;
    float sp = 0.f;
    for (int j = beg + slot; j < end; j += 4) {
        const float p = csr_p[j];
        const int d = edrec[j].y;
        const bf16x8 hv = *reinterpret_cast<const bf16x8*>(Hb + (size_t)d * 128 + tc * 8);
#pragma unroll
        for (int i = 0; i < 8; ++i) v[i] = fmaf(p, bf2f((ushort)hv[i]), v[i]);
        sp += p;
    }
#pragma unroll
    for (int m = 16; m <= 32; m <<= 1) {
#pragma unroll
        for (int i = 0; i < 8; ++i) v[i] += __shfl_xor(v[i], m, 64);
        sp += __shfl_xor(sp, m, 64);
    }
    if (lane < 16) {
        const float inv = (end > beg) ? 1.f / sp : 0.f;
        bf16x8 o;
#pragma unroll
        for (int i = 0; i < 8; ++i) o[i] = (short)f2bf(v[i] * inv);
        *reinterpret_cast<bf16x8*>(AGGb + (size_t)n * 128 + tc * 8) = o;
    }
}

// ---------------------------------------------------------------------------
// K4: o = agg @ W_out + b_out (MFMA) ; LayerNorm ; ReLU
// ---------------------------------------------------------------------------
__global__ __launch_bounds__(256) void k_out_ln(
    const ushort* __restrict__ AGGb, const ushort* __restrict__ packO,
    const float* __restrict__ b, const float* __restrict__ gamma,
    const float* __restrict__ beta, float* __restrict__ OUT)
{
    const int tid = threadIdx.x;
    const int wave = tid >> 6, lane = tid & 63;
    const int r = lane & 15, g = lane >> 4;
    const int nbase = blockIdx.x * 64 + wave * 16;
    const ushort* rowA = AGGb + (size_t)(nbase + r) * 128 + g * 8;
    const bf16x8* Bp = reinterpret_cast<const bf16x8*>(packO);

    f32x4 acc[8];
#pragma unroll
    for (int nt = 0; nt < 8; ++nt) {
        const float bv = b[nt * 16 + r];
        acc[nt] = (f32x4){bv, bv, bv, bv};
    }
#pragma unroll
    for (int k0 = 0; k0 < 4; ++k0) {
        const bf16x8 a = *reinterpret_cast<const bf16x8*>(rowA + k0 * 32);
#pragma unroll
        for (int nt = 0; nt < 8; ++nt)
            acc[nt] = __builtin_amdgcn_mfma_f32_16x16x32_bf16(
                a, Bp[(k0 * 8 + nt) * 64 + lane], acc[nt], 0, 0, 0);
    }

    float s1[4] = {0.f, 0.f, 0.f, 0.f};
    float s2[4] = {0.f, 0.f, 0.f, 0.f};
#pragma unroll
    for (int nt = 0; nt < 8; ++nt) {
#pragma unroll
        for (int q = 0; q < 4; ++q) {
            const float z = acc[nt][q];
            s1[q] += z;
            s2[q] = fmaf(z, z, s2[q]);
        }
    }
#pragma unroll
    for (int m = 1; m <= 8; m <<= 1) {
#pragma unroll
        for (int q = 0; q < 4; ++q) {
            s1[q] += __shfl_xor(s1[q], m, 64);
            s2[q] += __shfl_xor(s2[q], m, 64);
        }
    }
    float mu[4], rr[4];
#pragma unroll
    for (int q = 0; q < 4; ++q) {
        mu[q] = s1[q] * (1.f / 128.f);
        const float var = s2[q] * (1.f / 128.f) - mu[q] * mu[q];
        rr[q] = rsqrtf(var + 1e-5f);
    }
#pragma unroll
    for (int nt = 0; nt < 8; ++nt) {
        const int col = nt * 16 + r;
        const float ga = gamma[col], be = beta[col];
#pragma unroll
        for (int q = 0; q < 4; ++q) {
            const float o = (acc[nt][q] - mu[q]) * rr[q] * ga + be;
            OUT[(size_t)(nbase + g * 4 + q) * 128 + col] = o > 0.f ? o : 0.f;
        }
    }
}

// ---------------------------------------------------------------------------
extern "C" void kernel_launch(void* const* d_in, const int* in_sizes, int n_in,
                              void* d_out, int out_size, void* d_ws, size_t ws_size,
                              hipStream_t stream)
{
    const float* node_features = (const float*)d_in[0];
    const int*   edge_index    = (const int*)d_in[1];
    const float* edge_features = (const float*)d_in[2];
    const float* W_node  = (const float*)d_in[3];
    const float* b_node  = (const float*)d_in[4];
    const float* W_edge  = (const float*)d_in[5];
    const float* b_edge  = (const float*)d_in[6];
    const float* W_att1  = (const float*)d_in[7];
    const float* b_att1  = (const float*)d_in[8];
    const float* W_att2  = (const float*)d_in[9];
    const float* b_att2  = (const float*)d_in[10];
    const float* W_out   = (const float*)d_in[11];
    const float* b_out   = (const float*)d_in[12];
    const float* ln_gamma = (const float*)d_in[13];
    const float* ln_beta  = (const float*)d_in[14];
    float* out = (float*)d_out;

    // workspace layout (byte offsets, 16B-aligned)
    char* ws = (char*)d_ws;
    ushort* hb      = (ushort*)(ws);                   // 10,240,000 B
    ushort* G1      = (ushort*)(ws + 10240000);        // 10,240,000 B
    ushort* G2      = (ushort*)(ws + 20480000);        // 10,240,000 B
    ushort* aggb    = (ushort*)(ws + 30720000);        // 10,240,000 B
    float*  csr_p   = (float*)(ws + 40960000);         //  2,560,000 B
    int2*   edrec   = (int2*)(ws + 43520000);          //  5,120,000 B
    int*    rowptr  = (int*)(ws + 48640000);           //    160,004 B
    int*    cnt     = (int*)(ws + 48800016);           //    160,000 B
    int*    cursor  = (int*)(ws + 48960016);           //    160,000 B (contiguous after cnt)
    float*  Wc      = (float*)(ws + 49120016);         //     32,768 B
    float*  b_eff   = (float*)(ws + 49152784);         //        512 B
    ushort* packB   = (ushort*)(ws + 49153296);        //     65,536 B
    ushort* packA   = (ushort*)(ws + 49218832);        //     16,384 B
    ushort* packN   = (ushort*)(ws + 49235216);        //     32,768 B
    ushort* packO   = (ushort*)(ws + 49267984);        //     32,768 B

    const int* srcI = edge_index;
    const int* dstI = edge_index + N_EDGES;

    // zero histogram + fill cursors (contiguous)
    hipMemsetAsync(cnt, 0, 320000, stream);

    k_wcomb<<<33, 256, 0, stream>>>(W_edge, W_att1, b_att1, b_edge, Wc, b_eff);
    k_pack<<<288, 256, 0, stream>>>(W_att1, Wc, W_node, W_out,
                                    packB, packA, packN, packO);
    k_node_gemm<<<N_NODES / 64, 256, 0, stream>>>(node_features, packN, b_node, hb);
    k_node_g12<<<N_NODES / 64, 256, 0, stream>>>(hb, packB, b_eff, G1, G2);
    k_hist<<<N_EDGES / 256, 256, 0, stream>>>(srcI, cnt);
    k_scan<<<1, 1024, 0, stream>>>(cnt, rowptr);
    k_fill<<<N_EDGES / 256, 256, 0, stream>>>(srcI, dstI, rowptr, cursor, edrec);
    k_edge_att_v7<<<N_EDGES / 64, 256, 0, stream>>>(edrec, srcI, edge_features,
                                                    G1, G2, packA, W_att2, b_att2,
                                                    csr_p);
    k_agg<<<N_NODES / 4, 256, 0, stream>>>(rowptr, csr_p, edrec, hb, aggb);
    k_out_ln<<<N_NODES / 64, 256, 0, stream>>>(aggb, packO, b_out, ln_gamma, ln_beta, out);
}

// Round 17
// 257.350 us; speedup vs baseline: 1.0956x; 1.0154x over previous
//
#include <hip/hip_runtime.h>
#include <math.h>

#define N_NODES 40000
#define N_EDGES 640000
#define IN_DIM 128
#define EDGE_DIM 64
#define HID 128

typedef __attribute__((ext_vector_type(8))) short bf16x8;
typedef __attribute__((ext_vector_type(4))) float f32x4;

__device__ __forceinline__ ushort f2bf(float f) {
    unsigned int x = __float_as_uint(f);
    x += 0x7fffu + ((x >> 16) & 1u);
    return (ushort)(x >> 16);
}
__device__ __forceinline__ float bf2f(ushort u) {
    return __uint_as_float(((unsigned int)u) << 16);
}
// tanh(x) = 1 - 2/(e^{2x}+1); e^{2x}=inf -> 1, e^{2x}=0 -> -1 (no NaN)
__device__ __forceinline__ float tanh_fast(float x) {
    return 1.f - __fdividef(2.f, __expf(2.f * x) + 1.f);
}

// ---------------------------------------------------------------------------
// Setup A: W_comb = W_edge @ W1[256:384]; b_eff = b_att1 + b_edge @ W1he
// ---------------------------------------------------------------------------
__global__ __launch_bounds__(256) void k_wcomb(
    const float* __restrict__ W_edge, const float* __restrict__ W1,
    const float* __restrict__ b_att1, const float* __restrict__ b_edge,
    float* __restrict__ Wc, float* __restrict__ b_eff)
{
    const float* W1he = W1 + 256 * 128;
    if (blockIdx.x == 32) {
        const int n = threadIdx.x;
        if (n < 128) {
            float s = b_att1[n];
            for (int k = 0; k < 128; ++k) s = fmaf(b_edge[k], W1he[k * 128 + n], s);
            b_eff[n] = s;
        }
        return;
    }
    const int idx = blockIdx.x * 256 + threadIdx.x;
    const int row = idx >> 7, n = idx & 127;
    float s = 0.f;
    for (int k = 0; k < 128; ++k) s = fmaf(W_edge[row * 128 + k], W1he[k * 128 + n], s);
    Wc[idx] = s;
}

// ---------------------------------------------------------------------------
// Setup B: pack all weight fragments, bf16.
//  idx<32768          : packB  (B-op, W1 rows 0..255, G1/G2 GEMMs)
//  32768..40959       : packA  (A-op, Wc^T, edge GEMM)
//  40960..57343       : packN  (B-op, W_node)
//  57344..73727       : packO  (B-op, W_out)
// ---------------------------------------------------------------------------
__global__ __launch_bounds__(256) void k_pack(
    const float* __restrict__ W1, const float* __restrict__ Wc,
    const float* __restrict__ Wn, const float* __restrict__ Wo,
    ushort* __restrict__ packB, ushort* __restrict__ packA,
    ushort* __restrict__ packN, ushort* __restrict__ packO)
{
    const int idx = blockIdx.x * 256 + threadIdx.x;   // 0..73727
    if (idx < 32768) {
        const int j = idx & 7, lane = (idx >> 3) & 63, nt = (idx >> 9) & 7, k0 = idx >> 12;
        const int k = k0 * 32 + (lane >> 4) * 8 + j;
        const int n = nt * 16 + (lane & 15);
        packB[idx] = f2bf(W1[k * 128 + n]);
    } else if (idx < 40960) {
        const int i2 = idx - 32768;
        const int j = i2 & 7, lane = (i2 >> 3) & 63, mt = (i2 >> 9) & 7, k0 = i2 >> 12;
        const int k = k0 * 32 + (lane >> 4) * 8 + j;
        const int row = mt * 16 + (lane & 15);
        packA[i2] = f2bf(Wc[k * 128 + row]);
    } else if (idx < 57344) {
        const int i3 = idx - 40960;
        const int j = i3 & 7, lane = (i3 >> 3) & 63, nt = (i3 >> 9) & 7, k0 = i3 >> 12;
        const int k = k0 * 32 + (lane >> 4) * 8 + j;
        const int n = nt * 16 + (lane & 15);
        packN[i3] = f2bf(Wn[k * 128 + n]);
    } else {
        const int i4 = idx - 57344;
        const int j = i4 & 7, lane = (i4 >> 3) & 63, nt = (i4 >> 9) & 7, k0 = i4 >> 12;
        const int k = k0 * 32 + (lane >> 4) * 8 + j;
        const int n = nt * 16 + (lane & 15);
        packO[i4] = f2bf(Wo[k * 128 + n]);
    }
}

// ---------------------------------------------------------------------------
// K1: h = X @ W_node + b_node via MFMA (X fp32 -> bf16 on the fly); Hb bf16.
// ---------------------------------------------------------------------------
__global__ __launch_bounds__(256) void k_node_gemm(
    const float* __restrict__ X, const ushort* __restrict__ packN,
    const float* __restrict__ b, ushort* __restrict__ Hb)
{
    const int tid = threadIdx.x;
    const int wave = tid >> 6, lane = tid & 63;
    const int r = lane & 15, g = lane >> 4;
    const int nbase = blockIdx.x * 64 + wave * 16;
    const float* rowX = X + (size_t)(nbase + r) * 128 + g * 8;
    const bf16x8* Bp = reinterpret_cast<const bf16x8*>(packN);

    f32x4 acc[8];
#pragma unroll
    for (int nt = 0; nt < 8; ++nt) {
        const float bv = b[nt * 16 + r];
        acc[nt] = (f32x4){bv, bv, bv, bv};
    }
#pragma unroll
    for (int k0 = 0; k0 < 4; ++k0) {
        const float4 u0 = *reinterpret_cast<const float4*>(rowX + k0 * 32);
        const float4 u1 = *reinterpret_cast<const float4*>(rowX + k0 * 32 + 4);
        bf16x8 a;
        a[0] = (short)f2bf(u0.x); a[1] = (short)f2bf(u0.y);
        a[2] = (short)f2bf(u0.z); a[3] = (short)f2bf(u0.w);
        a[4] = (short)f2bf(u1.x); a[5] = (short)f2bf(u1.y);
        a[6] = (short)f2bf(u1.z); a[7] = (short)f2bf(u1.w);
#pragma unroll
        for (int nt = 0; nt < 8; ++nt)
            acc[nt] = __builtin_amdgcn_mfma_f32_16x16x32_bf16(
                a, Bp[(k0 * 8 + nt) * 64 + lane], acc[nt], 0, 0, 0);
    }
#pragma unroll
    for (int nt = 0; nt < 8; ++nt) {
#pragma unroll
        for (int q = 0; q < 4; ++q)
            Hb[(size_t)(nbase + g * 4 + q) * 128 + nt * 16 + r] = f2bf(acc[nt][q]);
    }
}

// ---------------------------------------------------------------------------
// K1b: G1 = Hb @ W1a + b_eff ; G2 = Hb @ W1b   (both [N,128] bf16)
// ---------------------------------------------------------------------------
__global__ __launch_bounds__(256) void k_node_g12(
    const ushort* __restrict__ Hb, const ushort* __restrict__ packB,
    const float* __restrict__ b_eff,
    ushort* __restrict__ G1, ushort* __restrict__ G2)
{
    const int tid = threadIdx.x;
    const int wave = tid >> 6, lane = tid & 63;
    const int r = lane & 15, g = lane >> 4;
    const int nbase = blockIdx.x * 64 + wave * 16;
    const ushort* rowA = Hb + (size_t)(nbase + r) * 128 + g * 8;
    const bf16x8* Bp = reinterpret_cast<const bf16x8*>(packB);

    f32x4 acc[8];
#pragma unroll
    for (int nt = 0; nt < 8; ++nt) acc[nt] = (f32x4){0.f, 0.f, 0.f, 0.f};
#pragma unroll
    for (int k0 = 0; k0 < 4; ++k0) {
        const bf16x8 a = *reinterpret_cast<const bf16x8*>(rowA + k0 * 32);
#pragma unroll
        for (int nt = 0; nt < 8; ++nt)
            acc[nt] = __builtin_amdgcn_mfma_f32_16x16x32_bf16(
                a, Bp[(k0 * 8 + nt) * 64 + lane], acc[nt], 0, 0, 0);
    }
#pragma unroll
    for (int nt = 0; nt < 8; ++nt) {
        const float bv = b_eff[nt * 16 + r];
#pragma unroll
        for (int q = 0; q < 4; ++q)
            G1[(size_t)(nbase + g * 4 + q) * 128 + nt * 16 + r] = f2bf(acc[nt][q] + bv);
    }

#pragma unroll
    for (int nt = 0; nt < 8; ++nt) acc[nt] = (f32x4){0.f, 0.f, 0.f, 0.f};
#pragma unroll
    for (int k0 = 0; k0 < 4; ++k0) {
        const bf16x8 a = *reinterpret_cast<const bf16x8*>(rowA + k0 * 32);
#pragma unroll
        for (int nt = 0; nt < 8; ++nt)
            acc[nt] = __builtin_amdgcn_mfma_f32_16x16x32_bf16(
                a, Bp[((k0 + 4) * 8 + nt) * 64 + lane], acc[nt], 0, 0, 0);
    }
#pragma unroll
    for (int nt = 0; nt < 8; ++nt) {
#pragma unroll
        for (int q = 0; q < 4; ++q)
            G2[(size_t)(nbase + g * 4 + q) * 128 + nt * 16 + r] = f2bf(acc[nt][q]);
    }
}

// ---------------------------------------------------------------------------
// CSR build: histogram -> single-block scan -> fill edrec = (e, si<<16|di)
// ---------------------------------------------------------------------------
__global__ __launch_bounds__(256) void k_hist(
    const int* __restrict__ srcI, int* __restrict__ cnt)
{
    const int e = blockIdx.x * 256 + threadIdx.x;
    atomicAdd(&cnt[srcI[e]], 1);
}

__global__ __launch_bounds__(1024) void k_scan(
    const int* __restrict__ cnt, int* __restrict__ rowptr)
{
    __shared__ int wsum[16];
    __shared__ int carry;
    const int tid = threadIdx.x, lane = tid & 63, wid = tid >> 6;
    if (tid == 0) { carry = 0; rowptr[0] = 0; }
    __syncthreads();
    for (int base = 0; base < N_NODES; base += 4096) {
        const int i = base + tid * 4;
        int4 c = {0, 0, 0, 0};
        if (i < N_NODES) c = *reinterpret_cast<const int4*>(cnt + i);
        const int tsum = c.x + c.y + c.z + c.w;
        int v = tsum;
#pragma unroll
        for (int d = 1; d < 64; d <<= 1) {
            const int t = __shfl_up(v, d, 64);
            if (lane >= d) v += t;
        }
        if (lane == 63) wsum[wid] = v;
        __syncthreads();
        if (wid == 0 && lane < 16) {
            int w = wsum[lane];
#pragma unroll
            for (int d = 1; d < 16; d <<= 1) {
                const int t = __shfl_up(w, d, 16);
                if ((lane & 15) >= d) w += t;
            }
            wsum[lane] = w;
        }
        __syncthreads();
        const int off = (wid == 0) ? 0 : wsum[wid - 1];
        const int excl = carry + off + v - tsum;
        if (i < N_NODES) {
            rowptr[i + 1] = excl + c.x;
            rowptr[i + 2] = excl + c.x + c.y;
            rowptr[i + 3] = excl + c.x + c.y + c.z;
            rowptr[i + 4] = excl + tsum;
        }
        const int total = wsum[15];
        __syncthreads();
        if (tid == 0) carry += total;
        __syncthreads();
    }
}

__global__ __launch_bounds__(256) void k_fill(
    const int* __restrict__ srcI, const int* __restrict__ dstI,
    const int* __restrict__ rowptr, int* __restrict__ cursor,
    int2* __restrict__ edrec)
{
    const int e = blockIdx.x * 256 + threadIdx.x;
    const int s = srcI[e];
    const int pos = rowptr[s] + atomicAdd(&cursor[s], 1);
    int2 rec;
    rec.x = e;
    rec.y = (s << 16) | dstI[e];   // both < 40000 < 2^16
    edrec[pos] = rec;              // single 8B scattered store
}

// ---------------------------------------------------------------------------
// K2 v8: CSR-ordered edge attention. si/di unpacked from edrec.y (no srcI
// gather). G1[si]+G2[di] folded into the MFMA accumulator INIT (no hoisted
// gather registers; adds absorbed by MFMA accumulation).
// z^T = Wc^T@EF[e]^T + (G1+G2); tanh; dot W2; exp; coalesced csr_p store.
// ---------------------------------------------------------------------------
__global__ __launch_bounds__(256) void k_edge_att_v8(
    const int2* __restrict__ edrec, const float* __restrict__ EF,
    const ushort* __restrict__ G1, const ushort* __restrict__ G2,
    const ushort* __restrict__ packA,
    const float* __restrict__ W2, const float* __restrict__ b2,
    float* __restrict__ csr_p)
{
    const int tid = threadIdx.x;
    const int wave = tid >> 6, lane = tid & 63;
    const int r = lane & 15, g = lane >> 4;
    const int pbase = blockIdx.x * 64 + wave * 16;
    const int pos = pbase + r;
    const int2 rec = edrec[pos];
    const int e = rec.x;
    const int di = rec.y & 0xffff;
    const int si = ((unsigned)rec.y) >> 16;

    // acc init = G1[si] + G2[di] in accumulator layout (bf16 -> f32 adds)
    const ushort* g1row = G1 + (size_t)si * 128 + g * 4;
    const ushort* g2row = G2 + (size_t)di * 128 + g * 4;
    f32x4 acc[8];
#pragma unroll
    for (int mt = 0; mt < 8; ++mt) {
        const ushort4 a = *reinterpret_cast<const ushort4*>(g1row + mt * 16);
        const ushort4 c = *reinterpret_cast<const ushort4*>(g2row + mt * 16);
        acc[mt][0] = bf2f(a.x) + bf2f(c.x);
        acc[mt][1] = bf2f(a.y) + bf2f(c.y);
        acc[mt][2] = bf2f(a.z) + bf2f(c.z);
        acc[mt][3] = bf2f(a.w) + bf2f(c.w);
    }

    // B-frags: EF[e][32*k0 + 8g + j], fp32 -> bf16
    const float* rowE = EF + (size_t)e * 64 + g * 8;
    bf16x8 b0, b1;
    {
        const float4 u0 = *reinterpret_cast<const float4*>(rowE);
        const float4 u1 = *reinterpret_cast<const float4*>(rowE + 4);
        b0[0] = (short)f2bf(u0.x); b0[1] = (short)f2bf(u0.y);
        b0[2] = (short)f2bf(u0.z); b0[3] = (short)f2bf(u0.w);
        b0[4] = (short)f2bf(u1.x); b0[5] = (short)f2bf(u1.y);
        b0[6] = (short)f2bf(u1.z); b0[7] = (short)f2bf(u1.w);
        const float4 v0 = *reinterpret_cast<const float4*>(rowE + 32);
        const float4 v1 = *reinterpret_cast<const float4*>(rowE + 36);
        b1[0] = (short)f2bf(v0.x); b1[1] = (short)f2bf(v0.y);
        b1[2] = (short)f2bf(v0.z); b1[3] = (short)f2bf(v0.w);
        b1[4] = (short)f2bf(v1.x); b1[5] = (short)f2bf(v1.y);
        b1[6] = (short)f2bf(v1.z); b1[7] = (short)f2bf(v1.w);
    }

    const bf16x8* Ap = reinterpret_cast<const bf16x8*>(packA);  // 16 KB, L2-hot
#pragma unroll
    for (int mt = 0; mt < 8; ++mt)
        acc[mt] = __builtin_amdgcn_mfma_f32_16x16x32_bf16(
            Ap[(0 * 8 + mt) * 64 + lane], b0, acc[mt], 0, 0, 0);
#pragma unroll
    for (int mt = 0; mt < 8; ++mt)
        acc[mt] = __builtin_amdgcn_mfma_f32_16x16x32_bf16(
            Ap[(1 * 8 + mt) * 64 + lane], b1, acc[mt], 0, 0, 0);

    // a = sum tanh(z)*W2 ; reduce over 4 g-groups ; p = exp(a + b2)
    float part = 0.f;
#pragma unroll
    for (int mt = 0; mt < 8; ++mt) {
        const float4 w2v = *reinterpret_cast<const float4*>(W2 + mt * 16 + g * 4);
        part = fmaf(tanh_fast(acc[mt][0]), w2v.x, part);
        part = fmaf(tanh_fast(acc[mt][1]), w2v.y, part);
        part = fmaf(tanh_fast(acc[mt][2]), w2v.z, part);
        part = fmaf(tanh_fast(acc[mt][3]), w2v.w, part);
    }
    part += __shfl_xor(part, 16, 64);
    part += __shfl_xor(part, 32, 64);
    if (lane < 16) csr_p[pos] = __expf(part + b2[0]);
}

// ---------------------------------------------------------------------------
// K3: per-node gather-aggregate, wave-per-node; 4 edge-slots x 16 col-lanes,
// 16B bf16x8 loads; (csr_p, edrec) streams; bf16 out.
// ---------------------------------------------------------------------------
__global__ __launch_bounds__(256) void k_agg(
    const int* __restrict__ rowptr, const float* __restrict__ csr_p,
    const int2* __restrict__ edrec, const ushort* __restrict__ Hb,
    ushort* __restrict__ AGGb)
{
    const int tid = threadIdx.x;
    const int wave = tid >> 6, lane = tid & 63;
    const int slot = lane >> 4, tc = lane & 15;
    const int n = blockIdx.x * 4 + wave;
    const int beg = rowptr[n], end = rowptr[n + 1];

    float v[8];
#pragma unroll
    for (int i = 0; i < 8; ++i) v[i] = 0.f;
    float sp = 0.f;
    for (int j = beg + slot; j < end; j += 4) {
        const float p = csr_p[j];
        const int d = edrec[j].y & 0xffff;
        const bf16x8 hv = *reinterpret_cast<const bf16x8*>(Hb + (size_t)d * 128 + tc * 8);
#pragma unroll
        for (int i = 0; i < 8; ++i) v[i] = fmaf(p, bf2f((ushort)hv[i]), v[i]);
        sp += p;
    }
#pragma unroll
    for (int m = 16; m <= 32; m <<= 1) {
#pragma unroll
        for (int i = 0; i < 8; ++i) v[i] += __shfl_xor(v[i], m, 64);
        sp += __shfl_xor(sp, m, 64);
    }
    if (lane < 16) {
        const float inv = (end > beg) ? 1.f / sp : 0.f;
        bf16x8 o;
#pragma unroll
        for (int i = 0; i < 8; ++i) o[i] = (short)f2bf(v[i] * inv);
        *reinterpret_cast<bf16x8*>(AGGb + (size_t)n * 128 + tc * 8) = o;
    }
}

// ---------------------------------------------------------------------------
// K4: o = agg @ W_out + b_out (MFMA) ; LayerNorm ; ReLU
// ---------------------------------------------------------------------------
__global__ __launch_bounds__(256) void k_out_ln(
    const ushort* __restrict__ AGGb, const ushort* __restrict__ packO,
    const float* __restrict__ b, const float* __restrict__ gamma,
    const float* __restrict__ beta, float* __restrict__ OUT)
{
    const int tid = threadIdx.x;
    const int wave = tid >> 6, lane = tid & 63;
    const int r = lane & 15, g = lane >> 4;
    const int nbase = blockIdx.x * 64 + wave * 16;
    const ushort* rowA = AGGb + (size_t)(nbase + r) * 128 + g * 8;
    const bf16x8* Bp = reinterpret_cast<const bf16x8*>(packO);

    f32x4 acc[8];
#pragma unroll
    for (int nt = 0; nt < 8; ++nt) {
        const float bv = b[nt * 16 + r];
        acc[nt] = (f32x4){bv, bv, bv, bv};
    }
#pragma unroll
    for (int k0 = 0; k0 < 4; ++k0) {
        const bf16x8 a = *reinterpret_cast<const bf16x8*>(rowA + k0 * 32);
#pragma unroll
        for (int nt = 0; nt < 8; ++nt)
            acc[nt] = __builtin_amdgcn_mfma_f32_16x16x32_bf16(
                a, Bp[(k0 * 8 + nt) * 64 + lane], acc[nt], 0, 0, 0);
    }

    float s1[4] = {0.f, 0.f, 0.f, 0.f};
    float s2[4] = {0.f, 0.f, 0.f, 0.f};
#pragma unroll
    for (int nt = 0; nt < 8; ++nt) {
#pragma unroll
        for (int q = 0; q < 4; ++q) {
            const float z = acc[nt][q];
            s1[q] += z;
            s2[q] = fmaf(z, z, s2[q]);
        }
    }
#pragma unroll
    for (int m = 1; m <= 8; m <<= 1) {
#pragma unroll
        for (int q = 0; q < 4; ++q) {
            s1[q] += __shfl_xor(s1[q], m, 64);
            s2[q] += __shfl_xor(s2[q], m, 64);
        }
    }
    float mu[4], rr[4];
#pragma unroll
    for (int q = 0; q < 4; ++q) {
        mu[q] = s1[q] * (1.f / 128.f);
        const float var = s2[q] * (1.f / 128.f) - mu[q] * mu[q];
        rr[q] = rsqrtf(var + 1e-5f);
    }
#pragma unroll
    for (int nt = 0; nt < 8; ++nt) {
        const int col = nt * 16 + r;
        const float ga = gamma[col], be = beta[col];
#pragma unroll
        for (int q = 0; q < 4; ++q) {
            const float o = (acc[nt][q] - mu[q]) * rr[q] * ga + be;
            OUT[(size_t)(nbase + g * 4 + q) * 128 + col] = o > 0.f ? o : 0.f;
        }
    }
}

// ---------------------------------------------------------------------------
extern "C" void kernel_launch(void* const* d_in, const int* in_sizes, int n_in,
                              void* d_out, int out_size, void* d_ws, size_t ws_size,
                              hipStream_t stream)
{
    const float* node_features = (const float*)d_in[0];
    const int*   edge_index    = (const int*)d_in[1];
    const float* edge_features = (const float*)d_in[2];
    const float* W_node  = (const float*)d_in[3];
    const float* b_node  = (const float*)d_in[4];
    const float* W_edge  = (const float*)d_in[5];
    const float* b_edge  = (const float*)d_in[6];
    const float* W_att1  = (const float*)d_in[7];
    const float* b_att1  = (const float*)d_in[8];
    const float* W_att2  = (const float*)d_in[9];
    const float* b_att2  = (const float*)d_in[10];
    const float* W_out   = (const float*)d_in[11];
    const float* b_out   = (const float*)d_in[12];
    const float* ln_gamma = (const float*)d_in[13];
    const float* ln_beta  = (const float*)d_in[14];
    float* out = (float*)d_out;

    // workspace layout (byte offsets, 16B-aligned)
    char* ws = (char*)d_ws;
    ushort* hb      = (ushort*)(ws);                   // 10,240,000 B
    ushort* G1      = (ushort*)(ws + 10240000);        // 10,240,000 B
    ushort* G2      = (ushort*)(ws + 20480000);        // 10,240,000 B
    ushort* aggb    = (ushort*)(ws + 30720000);        // 10,240,000 B
    float*  csr_p   = (float*)(ws + 40960000);         //  2,560,000 B
    int2*   edrec   = (int2*)(ws + 43520000);          //  5,120,000 B
    int*    rowptr  = (int*)(ws + 48640000);           //    160,004 B
    int*    cnt     = (int*)(ws + 48800016);           //    160,000 B
    int*    cursor  = (int*)(ws + 48960016);           //    160,000 B (contiguous after cnt)
    float*  Wc      = (float*)(ws + 49120016);         //     32,768 B
    float*  b_eff   = (float*)(ws + 49152784);         //        512 B
    ushort* packB   = (ushort*)(ws + 49153296);        //     65,536 B
    ushort* packA   = (ushort*)(ws + 49218832);        //     16,384 B
    ushort* packN   = (ushort*)(ws + 49235216);        //     32,768 B
    ushort* packO   = (ushort*)(ws + 49267984);        //     32,768 B

    const int* srcI = edge_index;
    const int* dstI = edge_index + N_EDGES;

    // zero histogram + fill cursors (contiguous)
    hipMemsetAsync(cnt, 0, 320000, stream);

    k_wcomb<<<33, 256, 0, stream>>>(W_edge, W_att1, b_att1, b_edge, Wc, b_eff);
    k_pack<<<288, 256, 0, stream>>>(W_att1, Wc, W_node, W_out,
                                    packB, packA, packN, packO);
    k_node_gemm<<<N_NODES / 64, 256, 0, stream>>>(node_features, packN, b_node, hb);
    k_node_g12<<<N_NODES / 64, 256, 0, stream>>>(hb, packB, b_eff, G1, G2);
    k_hist<<<N_EDGES / 256, 256, 0, stream>>>(srcI, cnt);
    k_scan<<<1, 1024, 0, stream>>>(cnt, rowptr);
    k_fill<<<N_EDGES / 256, 256, 0, stream>>>(srcI, dstI, rowptr, cursor, edrec);
    k_edge_att_v8<<<N_EDGES / 64, 256, 0, stream>>>(edrec, edge_features,
                                                    G1, G2, packA, W_att2, b_att2,
                                                    csr_p);
    k_agg<<<N_NODES / 4, 256, 0, stream>>>(rowptr, csr_p, edrec, hb, aggb);
    k_out_ln<<<N_NODES / 64, 256, 0, stream>>>(aggb, packO, b_out, ln_gamma, ln_beta, out);
}

// Round 18
// 243.787 us; speedup vs baseline: 1.1566x; 1.0556x over previous
//
#include <hip/hip_runtime.h>
#include <math.h>

#define N_NODES 40000
#define N_EDGES 640000
#define IN_DIM 128
#define EDGE_DIM 64
#define HID 128

typedef __attribute__((ext_vector_type(8))) short bf16x8;
typedef __attribute__((ext_vector_type(4))) float f32x4;

__device__ __forceinline__ ushort f2bf(float f) {
    unsigned int x = __float_as_uint(f);
    x += 0x7fffu + ((x >> 16) & 1u);
    return (ushort)(x >> 16);
}
__device__ __forceinline__ float bf2f(ushort u) {
    return __uint_as_float(((unsigned int)u) << 16);
}
// tanh(x) = 1 - 2/(e^{2x}+1); e^{2x}=inf -> 1, e^{2x}=0 -> -1 (no NaN)
__device__ __forceinline__ float tanh_fast(float x) {
    return 1.f - __fdividef(2.f, __expf(2.f * x) + 1.f);
}

// ---------------------------------------------------------------------------
// Setup A: W_comb = W_edge @ W1[256:384]; b_eff = b_att1 + b_edge @ W1he
// ---------------------------------------------------------------------------
__global__ __launch_bounds__(256) void k_wcomb(
    const float* __restrict__ W_edge, const float* __restrict__ W1,
    const float* __restrict__ b_att1, const float* __restrict__ b_edge,
    float* __restrict__ Wc, float* __restrict__ b_eff)
{
    const float* W1he = W1 + 256 * 128;
    if (blockIdx.x == 32) {
        const int n = threadIdx.x;
        if (n < 128) {
            float s = b_att1[n];
            for (int k = 0; k < 128; ++k) s = fmaf(b_edge[k], W1he[k * 128 + n], s);
            b_eff[n] = s;
        }
        return;
    }
    const int idx = blockIdx.x * 256 + threadIdx.x;
    const int row = idx >> 7, n = idx & 127;
    float s = 0.f;
    for (int k = 0; k < 128; ++k) s = fmaf(W_edge[row * 128 + k], W1he[k * 128 + n], s);
    Wc[idx] = s;
}

// ---------------------------------------------------------------------------
// Setup B: pack all weight fragments, bf16.
//  idx<32768          : packB  (B-op, W1 rows 0..255, G1/G2 GEMMs)
//  32768..40959       : packA  (A-op, Wc^T, edge GEMM)
//  40960..57343       : packN  (B-op, W_node)
//  57344..73727       : packO  (B-op, W_out)
// ---------------------------------------------------------------------------
__global__ __launch_bounds__(256) void k_pack(
    const float* __restrict__ W1, const float* __restrict__ Wc,
    const float* __restrict__ Wn, const float* __restrict__ Wo,
    ushort* __restrict__ packB, ushort* __restrict__ packA,
    ushort* __restrict__ packN, ushort* __restrict__ packO)
{
    const int idx = blockIdx.x * 256 + threadIdx.x;   // 0..73727
    if (idx < 32768) {
        const int j = idx & 7, lane = (idx >> 3) & 63, nt = (idx >> 9) & 7, k0 = idx >> 12;
        const int k = k0 * 32 + (lane >> 4) * 8 + j;
        const int n = nt * 16 + (lane & 15);
        packB[idx] = f2bf(W1[k * 128 + n]);
    } else if (idx < 40960) {
        const int i2 = idx - 32768;
        const int j = i2 & 7, lane = (i2 >> 3) & 63, mt = (i2 >> 9) & 7, k0 = i2 >> 12;
        const int k = k0 * 32 + (lane >> 4) * 8 + j;
        const int row = mt * 16 + (lane & 15);
        packA[i2] = f2bf(Wc[k * 128 + row]);
    } else if (idx < 57344) {
        const int i3 = idx - 40960;
        const int j = i3 & 7, lane = (i3 >> 3) & 63, nt = (i3 >> 9) & 7, k0 = i3 >> 12;
        const int k = k0 * 32 + (lane >> 4) * 8 + j;
        const int n = nt * 16 + (lane & 15);
        packN[i3] = f2bf(Wn[k * 128 + n]);
    } else {
        const int i4 = idx - 57344;
        const int j = i4 & 7, lane = (i4 >> 3) & 63, nt = (i4 >> 9) & 7, k0 = i4 >> 12;
        const int k = k0 * 32 + (lane >> 4) * 8 + j;
        const int n = nt * 16 + (lane & 15);
        packO[i4] = f2bf(Wo[k * 128 + n]);
    }
}

// ---------------------------------------------------------------------------
// K1: h = X @ W_node + b_node via MFMA (X fp32 -> bf16 on the fly); Hb bf16.
// ---------------------------------------------------------------------------
__global__ __launch_bounds__(256) void k_node_gemm(
    const float* __restrict__ X, const ushort* __restrict__ packN,
    const float* __restrict__ b, ushort* __restrict__ Hb)
{
    const int tid = threadIdx.x;
    const int wave = tid >> 6, lane = tid & 63;
    const int r = lane & 15, g = lane >> 4;
    const int nbase = blockIdx.x * 64 + wave * 16;
    const float* rowX = X + (size_t)(nbase + r) * 128 + g * 8;
    const bf16x8* Bp = reinterpret_cast<const bf16x8*>(packN);

    f32x4 acc[8];
#pragma unroll
    for (int nt = 0; nt < 8; ++nt) {
        const float bv = b[nt * 16 + r];
        acc[nt] = (f32x4){bv, bv, bv, bv};
    }
#pragma unroll
    for (int k0 = 0; k0 < 4; ++k0) {
        const float4 u0 = *reinterpret_cast<const float4*>(rowX + k0 * 32);
        const float4 u1 = *reinterpret_cast<const float4*>(rowX + k0 * 32 + 4);
        bf16x8 a;
        a[0] = (short)f2bf(u0.x); a[1] = (short)f2bf(u0.y);
        a[2] = (short)f2bf(u0.z); a[3] = (short)f2bf(u0.w);
        a[4] = (short)f2bf(u1.x); a[5] = (short)f2bf(u1.y);
        a[6] = (short)f2bf(u1.z); a[7] = (short)f2bf(u1.w);
#pragma unroll
        for (int nt = 0; nt < 8; ++nt)
            acc[nt] = __builtin_amdgcn_mfma_f32_16x16x32_bf16(
                a, Bp[(k0 * 8 + nt) * 64 + lane], acc[nt], 0, 0, 0);
    }
#pragma unroll
    for (int nt = 0; nt < 8; ++nt) {
#pragma unroll
        for (int q = 0; q < 4; ++q)
            Hb[(size_t)(nbase + g * 4 + q) * 128 + nt * 16 + r] = f2bf(acc[nt][q]);
    }
}

// ---------------------------------------------------------------------------
// K1b: G1 = Hb @ W1a + b_eff ; G2 = Hb @ W1b   (both [N,128] bf16)
// Stored PRE-PERMUTED for K2's accumulator-lane layout:
//   value at col = mt*16 + gc*4 + qc  is stored at row-offset gc*32 + mt*4 + qc
// so consumer lane (r,g) reads its 32-value slice as 4 contiguous bf16x8.
// Producer lane holds col = nt*16 + r  ->  gc=r>>2, qc=r&3, mt=nt.
// ---------------------------------------------------------------------------
__global__ __launch_bounds__(256) void k_node_g12(
    const ushort* __restrict__ Hb, const ushort* __restrict__ packB,
    const float* __restrict__ b_eff,
    ushort* __restrict__ G1, ushort* __restrict__ G2)
{
    const int tid = threadIdx.x;
    const int wave = tid >> 6, lane = tid & 63;
    const int r = lane & 15, g = lane >> 4;
    const int nbase = blockIdx.x * 64 + wave * 16;
    const ushort* rowA = Hb + (size_t)(nbase + r) * 128 + g * 8;
    const bf16x8* Bp = reinterpret_cast<const bf16x8*>(packB);
    const int coff = (r >> 2) * 32 + (r & 3);   // permuted base offset for this lane's col

    f32x4 acc[8];
#pragma unroll
    for (int nt = 0; nt < 8; ++nt) acc[nt] = (f32x4){0.f, 0.f, 0.f, 0.f};
#pragma unroll
    for (int k0 = 0; k0 < 4; ++k0) {
        const bf16x8 a = *reinterpret_cast<const bf16x8*>(rowA + k0 * 32);
#pragma unroll
        for (int nt = 0; nt < 8; ++nt)
            acc[nt] = __builtin_amdgcn_mfma_f32_16x16x32_bf16(
                a, Bp[(k0 * 8 + nt) * 64 + lane], acc[nt], 0, 0, 0);
    }
#pragma unroll
    for (int nt = 0; nt < 8; ++nt) {
        const float bv = b_eff[nt * 16 + r];
#pragma unroll
        for (int q = 0; q < 4; ++q)
            G1[(size_t)(nbase + g * 4 + q) * 128 + coff + nt * 4] = f2bf(acc[nt][q] + bv);
    }

#pragma unroll
    for (int nt = 0; nt < 8; ++nt) acc[nt] = (f32x4){0.f, 0.f, 0.f, 0.f};
#pragma unroll
    for (int k0 = 0; k0 < 4; ++k0) {
        const bf16x8 a = *reinterpret_cast<const bf16x8*>(rowA + k0 * 32);
#pragma unroll
        for (int nt = 0; nt < 8; ++nt)
            acc[nt] = __builtin_amdgcn_mfma_f32_16x16x32_bf16(
                a, Bp[((k0 + 4) * 8 + nt) * 64 + lane], acc[nt], 0, 0, 0);
    }
#pragma unroll
    for (int nt = 0; nt < 8; ++nt) {
#pragma unroll
        for (int q = 0; q < 4; ++q)
            G2[(size_t)(nbase + g * 4 + q) * 128 + coff + nt * 4] = f2bf(acc[nt][q]);
    }
}

// ---------------------------------------------------------------------------
// CSR build: histogram -> single-block scan -> fill edrec = (e, si<<16|di)
// ---------------------------------------------------------------------------
__global__ __launch_bounds__(256) void k_hist(
    const int* __restrict__ srcI, int* __restrict__ cnt)
{
    const int e = blockIdx.x * 256 + threadIdx.x;
    atomicAdd(&cnt[srcI[e]], 1);
}

__global__ __launch_bounds__(1024) void k_scan(
    const int* __restrict__ cnt, int* __restrict__ rowptr)
{
    __shared__ int wsum[16];
    __shared__ int carry;
    const int tid = threadIdx.x, lane = tid & 63, wid = tid >> 6;
    if (tid == 0) { carry = 0; rowptr[0] = 0; }
    __syncthreads();
    for (int base = 0; base < N_NODES; base += 4096) {
        const int i = base + tid * 4;
        int4 c = {0, 0, 0, 0};
        if (i < N_NODES) c = *reinterpret_cast<const int4*>(cnt + i);
        const int tsum = c.x + c.y + c.z + c.w;
        int v = tsum;
#pragma unroll
        for (int d = 1; d < 64; d <<= 1) {
            const int t = __shfl_up(v, d, 64);
            if (lane >= d) v += t;
        }
        if (lane == 63) wsum[wid] = v;
        __syncthreads();
        if (wid == 0 && lane < 16) {
            int w = wsum[lane];
#pragma unroll
            for (int d = 1; d < 16; d <<= 1) {
                const int t = __shfl_up(w, d, 16);
                if ((lane & 15) >= d) w += t;
            }
            wsum[lane] = w;
        }
        __syncthreads();
        const int off = (wid == 0) ? 0 : wsum[wid - 1];
        const int excl = carry + off + v - tsum;
        if (i < N_NODES) {
            rowptr[i + 1] = excl + c.x;
            rowptr[i + 2] = excl + c.x + c.y;
            rowptr[i + 3] = excl + c.x + c.y + c.z;
            rowptr[i + 4] = excl + tsum;
        }
        const int total = wsum[15];
        __syncthreads();
        if (tid == 0) carry += total;
        __syncthreads();
    }
}

__global__ __launch_bounds__(256) void k_fill(
    const int* __restrict__ srcI, const int* __restrict__ dstI,
    const int* __restrict__ rowptr, int* __restrict__ cursor,
    int2* __restrict__ edrec)
{
    const int e = blockIdx.x * 256 + threadIdx.x;
    const int s = srcI[e];
    const int pos = rowptr[s] + atomicAdd(&cursor[s], 1);
    int2 rec;
    rec.x = e;
    rec.y = (s << 16) | dstI[e];   // both < 40000 < 2^16
    edrec[pos] = rec;              // single 8B scattered store
}

// ---------------------------------------------------------------------------
// K2 v9: CSR-ordered edge attention. G1/G2 pre-permuted -> lane (r,g) reads
// its whole 32-value slice as 4 contiguous bf16x8 per table (one 64B region
// instead of 8 scattered 8B loads spanning 4 lines).
// z^T = Wc^T@EF[e]^T + (G1+G2); tanh; dot W2; exp; coalesced csr_p store.
// ---------------------------------------------------------------------------
__global__ __launch_bounds__(256) void k_edge_att_v9(
    const int2* __restrict__ edrec, const float* __restrict__ EF,
    const ushort* __restrict__ G1, const ushort* __restrict__ G2,
    const ushort* __restrict__ packA,
    const float* __restrict__ W2, const float* __restrict__ b2,
    float* __restrict__ csr_p)
{
    const int tid = threadIdx.x;
    const int wave = tid >> 6, lane = tid & 63;
    const int r = lane & 15, g = lane >> 4;
    const int pbase = blockIdx.x * 64 + wave * 16;
    const int pos = pbase + r;
    const int2 rec = edrec[pos];
    const int e = rec.x;
    const int di = rec.y & 0xffff;
    const int si = ((unsigned)rec.y) >> 16;

    // acc init = G1[si] + G2[di], permuted layout: 4 contiguous 16B loads each
    const ushort* g1base = G1 + (size_t)si * 128 + g * 32;
    const ushort* g2base = G2 + (size_t)di * 128 + g * 32;
    f32x4 acc[8];
#pragma unroll
    for (int mt2 = 0; mt2 < 4; ++mt2) {
        const bf16x8 a = *reinterpret_cast<const bf16x8*>(g1base + mt2 * 8);
        const bf16x8 c = *reinterpret_cast<const bf16x8*>(g2base + mt2 * 8);
#pragma unroll
        for (int q = 0; q < 4; ++q) {
            acc[2 * mt2][q]     = bf2f((ushort)a[q])     + bf2f((ushort)c[q]);
            acc[2 * mt2 + 1][q] = bf2f((ushort)a[4 + q]) + bf2f((ushort)c[4 + q]);
        }
    }

    // B-frags: EF[e][32*k0 + 8g + j], fp32 -> bf16
    const float* rowE = EF + (size_t)e * 64 + g * 8;
    bf16x8 b0, b1;
    {
        const float4 u0 = *reinterpret_cast<const float4*>(rowE);
        const float4 u1 = *reinterpret_cast<const float4*>(rowE + 4);
        b0[0] = (short)f2bf(u0.x); b0[1] = (short)f2bf(u0.y);
        b0[2] = (short)f2bf(u0.z); b0[3] = (short)f2bf(u0.w);
        b0[4] = (short)f2bf(u1.x); b0[5] = (short)f2bf(u1.y);
        b0[6] = (short)f2bf(u1.z); b0[7] = (short)f2bf(u1.w);
        const float4 v0 = *reinterpret_cast<const float4*>(rowE + 32);
        const float4 v1 = *reinterpret_cast<const float4*>(rowE + 36);
        b1[0] = (short)f2bf(v0.x); b1[1] = (short)f2bf(v0.y);
        b1[2] = (short)f2bf(v0.z); b1[3] = (short)f2bf(v0.w);
        b1[4] = (short)f2bf(v1.x); b1[5] = (short)f2bf(v1.y);
        b1[6] = (short)f2bf(v1.z); b1[7] = (short)f2bf(v1.w);
    }

    const bf16x8* Ap = reinterpret_cast<const bf16x8*>(packA);  // 16 KB, L2-hot
#pragma unroll
    for (int mt = 0; mt < 8; ++mt)
        acc[mt] = __builtin_amdgcn_mfma_f32_16x16x32_bf16(
            Ap[(0 * 8 + mt) * 64 + lane], b0, acc[mt], 0, 0, 0);
#pragma unroll
    for (int mt = 0; mt < 8; ++mt)
        acc[mt] = __builtin_amdgcn_mfma_f32_16x16x32_bf16(
            Ap[(1 * 8 + mt) * 64 + lane], b1, acc[mt], 0, 0, 0);

    // a = sum tanh(z)*W2 ; reduce over 4 g-groups ; p = exp(a + b2)
    float part = 0.f;
#pragma unroll
    for (int mt = 0; mt < 8; ++mt) {
        const float4 w2v = *reinterpret_cast<const float4*>(W2 + mt * 16 + g * 4);
        part = fmaf(tanh_fast(acc[mt][0]), w2v.x, part);
        part = fmaf(tanh_fast(acc[mt][1]), w2v.y, part);
        part = fmaf(tanh_fast(acc[mt][2]), w2v.z, part);
        part = fmaf(tanh_fast(acc[mt][3]), w2v.w, part);
    }
    part += __shfl_xor(part, 16, 64);
    part += __shfl_xor(part, 32, 64);
    if (lane < 16) csr_p[pos] = __expf(part + b2[0]);
}

// ---------------------------------------------------------------------------
// K3: per-node gather-aggregate, wave-per-node; 4 edge-slots x 16 col-lanes,
// 16B bf16x8 loads; (csr_p, edrec) streams; bf16 out.
// ---------------------------------------------------------------------------
__global__ __launch_bounds__(256) void k_agg(
    const int* __restrict__ rowptr, const float* __restrict__ csr_p,
    const int2* __restrict__ edrec, const ushort* __restrict__ Hb,
    ushort* __restrict__ AGGb)
{
    const int tid = threadIdx.x;
    const int wave = tid >> 6, lane = tid & 63;
    const int slot = lane >> 4, tc = lane & 15;
    const int n = blockIdx.x * 4 + wave;
    const int beg = rowptr[n], end = rowptr[n + 1];

    float v[8];
#pragma unroll
    for (int i = 0; i < 8; ++i) v[i] = 0.f;
    float sp = 0.f;
    for (int j = beg + slot; j < end; j += 4) {
        const float p = csr_p[j];
        const int d = edrec[j].y & 0xffff;
        const bf16x8 hv = *reinterpret_cast<const bf16x8*>(Hb + (size_t)d * 128 + tc * 8);
#pragma unroll
        for (int i = 0; i < 8; ++i) v[i] = fmaf(p, bf2f((ushort)hv[i]), v[i]);
        sp += p;
    }
#pragma unroll
    for (int m = 16; m <= 32; m <<= 1) {
#pragma unroll
        for (int i = 0; i < 8; ++i) v[i] += __shfl_xor(v[i], m, 64);
        sp += __shfl_xor(sp, m, 64);
    }
    if (lane < 16) {
        const float inv = (end > beg) ? 1.f / sp : 0.f;
        bf16x8 o;
#pragma unroll
        for (int i = 0; i < 8; ++i) o[i] = (short)f2bf(v[i] * inv);
        *reinterpret_cast<bf16x8*>(AGGb + (size_t)n * 128 + tc * 8) = o;
    }
}

// ---------------------------------------------------------------------------
// K4: o = agg @ W_out + b_out (MFMA) ; LayerNorm ; ReLU
// ---------------------------------------------------------------------------
__global__ __launch_bounds__(256) void k_out_ln(
    const ushort* __restrict__ AGGb, const ushort* __restrict__ packO,
    const float* __restrict__ b, const float* __restrict__ gamma,
    const float* __restrict__ beta, float* __restrict__ OUT)
{
    const int tid = threadIdx.x;
    const int wave = tid >> 6, lane = tid & 63;
    const int r = lane & 15, g = lane >> 4;
    const int nbase = blockIdx.x * 64 + wave * 16;
    const ushort* rowA = AGGb + (size_t)(nbase + r) * 128 + g * 8;
    const bf16x8* Bp = reinterpret_cast<const bf16x8*>(packO);

    f32x4 acc[8];
#pragma unroll
    for (int nt = 0; nt < 8; ++nt) {
        const float bv = b[nt * 16 + r];
        acc[nt] = (f32x4){bv, bv, bv, bv};
    }
#pragma unroll
    for (int k0 = 0; k0 < 4; ++k0) {
        const bf16x8 a = *reinterpret_cast<const bf16x8*>(rowA + k0 * 32);
#pragma unroll
        for (int nt = 0; nt < 8; ++nt)
            acc[nt] = __builtin_amdgcn_mfma_f32_16x16x32_bf16(
                a, Bp[(k0 * 8 + nt) * 64 + lane], acc[nt], 0, 0, 0);
    }

    float s1[4] = {0.f, 0.f, 0.f, 0.f};
    float s2[4] = {0.f, 0.f, 0.f, 0.f};
#pragma unroll
    for (int nt = 0; nt < 8; ++nt) {
#pragma unroll
        for (int q = 0; q < 4; ++q) {
            const float z = acc[nt][q];
            s1[q] += z;
            s2[q] = fmaf(z, z, s2[q]);
        }
    }
#pragma unroll
    for (int m = 1; m <= 8; m <<= 1) {
#pragma unroll
        for (int q = 0; q < 4; ++q) {
            s1[q] += __shfl_xor(s1[q], m, 64);
            s2[q] += __shfl_xor(s2[q], m, 64);
        }
    }
    float mu[4], rr[4];
#pragma unroll
    for (int q = 0; q < 4; ++q) {
        mu[q] = s1[q] * (1.f / 128.f);
        const float var = s2[q] * (1.f / 128.f) - mu[q] * mu[q];
        rr[q] = rsqrtf(var + 1e-5f);
    }
#pragma unroll
    for (int nt = 0; nt < 8; ++nt) {
        const int col = nt * 16 + r;
        const float ga = gamma[col], be = beta[col];
#pragma unroll
        for (int q = 0; q < 4; ++q) {
            const float o = (acc[nt][q] - mu[q]) * rr[q] * ga + be;
            OUT[(size_t)(nbase + g * 4 + q) * 128 + col] = o > 0.f ? o : 0.f;
        }
    }
}

// ---------------------------------------------------------------------------
extern "C" void kernel_launch(void* const* d_in, const int* in_sizes, int n_in,
                              void* d_out, int out_size, void* d_ws, size_t ws_size,
                              hipStream_t stream)
{
    const float* node_features = (const float*)d_in[0];
    const int*   edge_index    = (const int*)d_in[1];
    const float* edge_features = (const float*)d_in[2];
    const float* W_node  = (const float*)d_in[3];
    const float* b_node  = (const float*)d_in[4];
    const float* W_edge  = (const float*)d_in[5];
    const float* b_edge  = (const float*)d_in[6];
    const float* W_att1  = (const float*)d_in[7];
    const float* b_att1  = (const float*)d_in[8];
    const float* W_att2  = (const float*)d_in[9];
    const float* b_att2  = (const float*)d_in[10];
    const float* W_out   = (const float*)d_in[11];
    const float* b_out   = (const float*)d_in[12];
    const float* ln_gamma = (const float*)d_in[13];
    const float* ln_beta  = (const float*)d_in[14];
    float* out = (float*)d_out;

    // workspace layout (byte offsets, 16B-aligned)
    char* ws = (char*)d_ws;
    ushort* hb      = (ushort*)(ws);                   // 10,240,000 B
    ushort* G1      = (ushort*)(ws + 10240000);        // 10,240,000 B
    ushort* G2      = (ushort*)(ws + 20480000);        // 10,240,000 B
    ushort* aggb    = (ushort*)(ws + 30720000);        // 10,240,000 B
    float*  csr_p   = (float*)(ws + 40960000);         //  2,560,000 B
    int2*   edrec   = (int2*)(ws + 43520000);          //  5,120,000 B
    int*    rowptr  = (int*)(ws + 48640000);           //    160,004 B
    int*    cnt     = (int*)(ws + 48800016);           //    160,000 B
    int*    cursor  = (int*)(ws + 48960016);           //    160,000 B (contiguous after cnt)
    float*  Wc      = (float*)(ws + 49120016);         //     32,768 B
    float*  b_eff   = (float*)(ws + 49152784);         //        512 B
    ushort* packB   = (ushort*)(ws + 49153296);        //     65,536 B
    ushort* packA   = (ushort*)(ws + 49218832);        //     16,384 B
    ushort* packN   = (ushort*)(ws + 49235216);        //     32,768 B
    ushort* packO   = (ushort*)(ws + 49267984);        //     32,768 B

    const int* srcI = edge_index;
    const int* dstI = edge_index + N_EDGES;

    // zero histogram + fill cursors (contiguous)
    hipMemsetAsync(cnt, 0, 320000, stream);

    k_wcomb<<<33, 256, 0, stream>>>(W_edge, W_att1, b_att1, b_edge, Wc, b_eff);
    k_pack<<<288, 256, 0, stream>>>(W_att1, Wc, W_node, W_out,
                                    packB, packA, packN, packO);
    k_node_gemm<<<N_NODES / 64, 256, 0, stream>>>(node_features, packN, b_node, hb);
    k_node_g12<<<N_NODES / 64, 256, 0, stream>>>(hb, packB, b_eff, G1, G2);
    k_hist<<<N_EDGES / 256, 256, 0, stream>>>(srcI, cnt);
    k_scan<<<1, 1024, 0, stream>>>(cnt, rowptr);
    k_fill<<<N_EDGES / 256, 256, 0, stream>>>(srcI, dstI, rowptr, cursor, edrec);
    k_edge_att_v9<<<N_EDGES / 64, 256, 0, stream>>>(edrec, edge_features,
                                                    G1, G2, packA, W_att2, b_att2,
                                                    csr_p);
    k_agg<<<N_NODES / 4, 256, 0, stream>>>(rowptr, csr_p, edrec, hb, aggb);
    k_out_ln<<<N_NODES / 64, 256, 0, stream>>>(aggb, packO, b_out, ln_gamma, ln_beta, out);
}

// Round 19
// 231.226 us; speedup vs baseline: 1.2194x; 1.0543x over previous
//
#include <hip/hip_runtime.h>
#include <math.h>

#define N_NODES 40000
#define N_EDGES 640000
#define IN_DIM 128
#define EDGE_DIM 64
#define HID 128

typedef __attribute__((ext_vector_type(8))) short bf16x8;
typedef __attribute__((ext_vector_type(4))) float f32x4;

__device__ __forceinline__ ushort f2bf(float f) {
    unsigned int x = __float_as_uint(f);
    x += 0x7fffu + ((x >> 16) & 1u);
    return (ushort)(x >> 16);
}
__device__ __forceinline__ float bf2f(ushort u) {
    return __uint_as_float(((unsigned int)u) << 16);
}
// tanh(x) = 1 - 2/(e^{2x}+1); e^{2x}=inf -> 1, e^{2x}=0 -> -1 (no NaN)
__device__ __forceinline__ float tanh_fast(float x) {
    return 1.f - __fdividef(2.f, __expf(2.f * x) + 1.f);
}

// ---------------------------------------------------------------------------
// Launch A (256 thr): blocks 0..32 = wcomb ; blocks 33..2532 = hist
// ---------------------------------------------------------------------------
__global__ __launch_bounds__(256) void k_A(
    const float* __restrict__ W_edge, const float* __restrict__ W1,
    const float* __restrict__ b_att1, const float* __restrict__ b_edge,
    float* __restrict__ Wc, float* __restrict__ b_eff,
    const int* __restrict__ srcI, int* __restrict__ cnt)
{
    const int bid = blockIdx.x;
    if (bid < 33) {
        // --- wcomb ---
        const float* W1he = W1 + 256 * 128;
        if (bid == 32) {
            const int n = threadIdx.x;
            if (n < 128) {
                float s = b_att1[n];
                for (int k = 0; k < 128; ++k) s = fmaf(b_edge[k], W1he[k * 128 + n], s);
                b_eff[n] = s;
            }
            return;
        }
        const int idx = bid * 256 + threadIdx.x;
        const int row = idx >> 7, n = idx & 127;
        float s = 0.f;
        for (int k = 0; k < 128; ++k) s = fmaf(W_edge[row * 128 + k], W1he[k * 128 + n], s);
        Wc[idx] = s;
    } else {
        // --- hist ---
        const int e = (bid - 33) * 256 + threadIdx.x;
        atomicAdd(&cnt[srcI[e]], 1);
    }
}

// ---------------------------------------------------------------------------
// Launch B (1024 thr): blocks 0..71 = pack (idx = b*1024+tid) ; block 72 = scan
// pack:  idx<32768 packB | <40960 packA | <57344 packN | <73728 packO
// ---------------------------------------------------------------------------
__global__ __launch_bounds__(1024) void k_B(
    const float* __restrict__ W1, const float* __restrict__ Wc,
    const float* __restrict__ Wn, const float* __restrict__ Wo,
    ushort* __restrict__ packB, ushort* __restrict__ packA,
    ushort* __restrict__ packN, ushort* __restrict__ packO,
    const int* __restrict__ cnt, int* __restrict__ rowptr)
{
    const int bid = blockIdx.x;
    if (bid < 72) {
        const int idx = bid * 1024 + threadIdx.x;   // 0..73727
        if (idx < 32768) {
            const int j = idx & 7, lane = (idx >> 3) & 63, nt = (idx >> 9) & 7, k0 = idx >> 12;
            const int k = k0 * 32 + (lane >> 4) * 8 + j;
            const int n = nt * 16 + (lane & 15);
            packB[idx] = f2bf(W1[k * 128 + n]);
        } else if (idx < 40960) {
            const int i2 = idx - 32768;
            const int j = i2 & 7, lane = (i2 >> 3) & 63, mt = (i2 >> 9) & 7, k0 = i2 >> 12;
            const int k = k0 * 32 + (lane >> 4) * 8 + j;
            const int row = mt * 16 + (lane & 15);
            packA[i2] = f2bf(Wc[k * 128 + row]);
        } else if (idx < 57344) {
            const int i3 = idx - 40960;
            const int j = i3 & 7, lane = (i3 >> 3) & 63, nt = (i3 >> 9) & 7, k0 = i3 >> 12;
            const int k = k0 * 32 + (lane >> 4) * 8 + j;
            const int n = nt * 16 + (lane & 15);
            packN[i3] = f2bf(Wn[k * 128 + n]);
        } else {
            const int i4 = idx - 57344;
            const int j = i4 & 7, lane = (i4 >> 3) & 63, nt = (i4 >> 9) & 7, k0 = i4 >> 12;
            const int k = k0 * 32 + (lane >> 4) * 8 + j;
            const int n = nt * 16 + (lane & 15);
            packO[i4] = f2bf(Wo[k * 128 + n]);
        }
        return;
    }
    // --- scan (single block, 1024 thr, 4 elems/thread) ---
    __shared__ int wsum[16];
    __shared__ int carry;
    const int tid = threadIdx.x, lane = tid & 63, wid = tid >> 6;
    if (tid == 0) { carry = 0; rowptr[0] = 0; }
    __syncthreads();
    for (int base = 0; base < N_NODES; base += 4096) {
        const int i = base + tid * 4;
        int4 c = {0, 0, 0, 0};
        if (i < N_NODES) c = *reinterpret_cast<const int4*>(cnt + i);
        const int tsum = c.x + c.y + c.z + c.w;
        int v = tsum;
#pragma unroll
        for (int d = 1; d < 64; d <<= 1) {
            const int t = __shfl_up(v, d, 64);
            if (lane >= d) v += t;
        }
        if (lane == 63) wsum[wid] = v;
        __syncthreads();
        if (wid == 0 && lane < 16) {
            int w = wsum[lane];
#pragma unroll
            for (int d = 1; d < 16; d <<= 1) {
                const int t = __shfl_up(w, d, 16);
                if ((lane & 15) >= d) w += t;
            }
            wsum[lane] = w;
        }
        __syncthreads();
        const int off = (wid == 0) ? 0 : wsum[wid - 1];
        const int excl = carry + off + v - tsum;
        if (i < N_NODES) {
            rowptr[i + 1] = excl + c.x;
            rowptr[i + 2] = excl + c.x + c.y;
            rowptr[i + 3] = excl + c.x + c.y + c.z;
            rowptr[i + 4] = excl + tsum;
        }
        const int total = wsum[15];
        __syncthreads();
        if (tid == 0) carry += total;
        __syncthreads();
    }
}

// ---------------------------------------------------------------------------
// Launch C (256 thr): blocks 0..624 = node_gemm ; blocks 625..3124 = fill
// ---------------------------------------------------------------------------
__global__ __launch_bounds__(256) void k_C(
    const float* __restrict__ X, const ushort* __restrict__ packN,
    const float* __restrict__ b, ushort* __restrict__ Hb,
    const int* __restrict__ srcI, const int* __restrict__ dstI,
    const int* __restrict__ rowptr, int* __restrict__ cursor,
    int2* __restrict__ edrec)
{
    const int bid = blockIdx.x;
    if (bid >= 625) {
        // --- fill: edrec[pos] = (e, si<<16|di), single 8B scattered store ---
        const int e = (bid - 625) * 256 + threadIdx.x;
        const int s = srcI[e];
        const int pos = rowptr[s] + atomicAdd(&cursor[s], 1);
        int2 rec;
        rec.x = e;
        rec.y = (s << 16) | dstI[e];
        edrec[pos] = rec;
        return;
    }
    // --- node_gemm: h = X @ W_node + b (MFMA), bf16 out ---
    const int tid = threadIdx.x;
    const int wave = tid >> 6, lane = tid & 63;
    const int r = lane & 15, g = lane >> 4;
    const int nbase = bid * 64 + wave * 16;
    const float* rowX = X + (size_t)(nbase + r) * 128 + g * 8;
    const bf16x8* Bp = reinterpret_cast<const bf16x8*>(packN);

    f32x4 acc[8];
#pragma unroll
    for (int nt = 0; nt < 8; ++nt) {
        const float bv = b[nt * 16 + r];
        acc[nt] = (f32x4){bv, bv, bv, bv};
    }
#pragma unroll
    for (int k0 = 0; k0 < 4; ++k0) {
        const float4 u0 = *reinterpret_cast<const float4*>(rowX + k0 * 32);
        const float4 u1 = *reinterpret_cast<const float4*>(rowX + k0 * 32 + 4);
        bf16x8 a;
        a[0] = (short)f2bf(u0.x); a[1] = (short)f2bf(u0.y);
        a[2] = (short)f2bf(u0.z); a[3] = (short)f2bf(u0.w);
        a[4] = (short)f2bf(u1.x); a[5] = (short)f2bf(u1.y);
        a[6] = (short)f2bf(u1.z); a[7] = (short)f2bf(u1.w);
#pragma unroll
        for (int nt = 0; nt < 8; ++nt)
            acc[nt] = __builtin_amdgcn_mfma_f32_16x16x32_bf16(
                a, Bp[(k0 * 8 + nt) * 64 + lane], acc[nt], 0, 0, 0);
    }
#pragma unroll
    for (int nt = 0; nt < 8; ++nt) {
#pragma unroll
        for (int q = 0; q < 4; ++q)
            Hb[(size_t)(nbase + g * 4 + q) * 128 + nt * 16 + r] = f2bf(acc[nt][q]);
    }
}

// ---------------------------------------------------------------------------
// K1b: G1 = Hb @ W1a + b_eff ; G2 = Hb @ W1b   (both [N,128] bf16)
// Stored PRE-PERMUTED for K2's accumulator-lane layout (coff mapping).
// ---------------------------------------------------------------------------
__global__ __launch_bounds__(256) void k_node_g12(
    const ushort* __restrict__ Hb, const ushort* __restrict__ packB,
    const float* __restrict__ b_eff,
    ushort* __restrict__ G1, ushort* __restrict__ G2)
{
    const int tid = threadIdx.x;
    const int wave = tid >> 6, lane = tid & 63;
    const int r = lane & 15, g = lane >> 4;
    const int nbase = blockIdx.x * 64 + wave * 16;
    const ushort* rowA = Hb + (size_t)(nbase + r) * 128 + g * 8;
    const bf16x8* Bp = reinterpret_cast<const bf16x8*>(packB);
    const int coff = (r >> 2) * 32 + (r & 3);

    f32x4 acc[8];
#pragma unroll
    for (int nt = 0; nt < 8; ++nt) acc[nt] = (f32x4){0.f, 0.f, 0.f, 0.f};
#pragma unroll
    for (int k0 = 0; k0 < 4; ++k0) {
        const bf16x8 a = *reinterpret_cast<const bf16x8*>(rowA + k0 * 32);
#pragma unroll
        for (int nt = 0; nt < 8; ++nt)
            acc[nt] = __builtin_amdgcn_mfma_f32_16x16x32_bf16(
                a, Bp[(k0 * 8 + nt) * 64 + lane], acc[nt], 0, 0, 0);
    }
#pragma unroll
    for (int nt = 0; nt < 8; ++nt) {
        const float bv = b_eff[nt * 16 + r];
#pragma unroll
        for (int q = 0; q < 4; ++q)
            G1[(size_t)(nbase + g * 4 + q) * 128 + coff + nt * 4] = f2bf(acc[nt][q] + bv);
    }

#pragma unroll
    for (int nt = 0; nt < 8; ++nt) acc[nt] = (f32x4){0.f, 0.f, 0.f, 0.f};
#pragma unroll
    for (int k0 = 0; k0 < 4; ++k0) {
        const bf16x8 a = *reinterpret_cast<const bf16x8*>(rowA + k0 * 32);
#pragma unroll
        for (int nt = 0; nt < 8; ++nt)
            acc[nt] = __builtin_amdgcn_mfma_f32_16x16x32_bf16(
                a, Bp[((k0 + 4) * 8 + nt) * 64 + lane], acc[nt], 0, 0, 0);
    }
#pragma unroll
    for (int nt = 0; nt < 8; ++nt) {
#pragma unroll
        for (int q = 0; q < 4; ++q)
            G2[(size_t)(nbase + g * 4 + q) * 128 + coff + nt * 4] = f2bf(acc[nt][q]);
    }
}

// ---------------------------------------------------------------------------
// K2 v10: CSR-ordered edge attention. G1 (L1-hot) folded into acc init;
// G2 (random) loads HOISTED to kernel start, held raw (16 VGPR), folded in
// at the tanh epilogue -> L3 gather latency overlaps EF-load + MFMA.
// ---------------------------------------------------------------------------
__global__ __launch_bounds__(256) void k_edge_att_v10(
    const int2* __restrict__ edrec, const float* __restrict__ EF,
    const ushort* __restrict__ G1, const ushort* __restrict__ G2,
    const ushort* __restrict__ packA,
    const float* __restrict__ W2, const float* __restrict__ b2,
    float* __restrict__ csr_p)
{
    const int tid = threadIdx.x;
    const int wave = tid >> 6, lane = tid & 63;
    const int r = lane & 15, g = lane >> 4;
    const int pbase = blockIdx.x * 64 + wave * 16;
    const int pos = pbase + r;
    const int2 rec = edrec[pos];
    const int e = rec.x;
    const int di = rec.y & 0xffff;
    const int si = ((unsigned)rec.y) >> 16;

    // hoisted random G2 loads (consumed in epilogue)
    const ushort* g2base = G2 + (size_t)di * 128 + g * 32;
    bf16x8 g2r[4];
#pragma unroll
    for (int m2 = 0; m2 < 4; ++m2)
        g2r[m2] = *reinterpret_cast<const bf16x8*>(g2base + m2 * 8);

    // acc init = G1[si] (L1-hot, CSR-local)
    const ushort* g1base = G1 + (size_t)si * 128 + g * 32;
    f32x4 acc[8];
#pragma unroll
    for (int m2 = 0; m2 < 4; ++m2) {
        const bf16x8 a = *reinterpret_cast<const bf16x8*>(g1base + m2 * 8);
#pragma unroll
        for (int q = 0; q < 4; ++q) {
            acc[2 * m2][q]     = bf2f((ushort)a[q]);
            acc[2 * m2 + 1][q] = bf2f((ushort)a[4 + q]);
        }
    }

    // B-frags: EF[e][32*k0 + 8g + j], fp32 -> bf16
    const float* rowE = EF + (size_t)e * 64 + g * 8;
    bf16x8 b0, b1;
    {
        const float4 u0 = *reinterpret_cast<const float4*>(rowE);
        const float4 u1 = *reinterpret_cast<const float4*>(rowE + 4);
        b0[0] = (short)f2bf(u0.x); b0[1] = (short)f2bf(u0.y);
        b0[2] = (short)f2bf(u0.z); b0[3] = (short)f2bf(u0.w);
        b0[4] = (short)f2bf(u1.x); b0[5] = (short)f2bf(u1.y);
        b0[6] = (short)f2bf(u1.z); b0[7] = (short)f2bf(u1.w);
        const float4 v0 = *reinterpret_cast<const float4*>(rowE + 32);
        const float4 v1 = *reinterpret_cast<const float4*>(rowE + 36);
        b1[0] = (short)f2bf(v0.x); b1[1] = (short)f2bf(v0.y);
        b1[2] = (short)f2bf(v0.z); b1[3] = (short)f2bf(v0.w);
        b1[4] = (short)f2bf(v1.x); b1[5] = (short)f2bf(v1.y);
        b1[6] = (short)f2bf(v1.z); b1[7] = (short)f2bf(v1.w);
    }

    const bf16x8* Ap = reinterpret_cast<const bf16x8*>(packA);  // 16 KB, L2-hot
#pragma unroll
    for (int mt = 0; mt < 8; ++mt)
        acc[mt] = __builtin_amdgcn_mfma_f32_16x16x32_bf16(
            Ap[(0 * 8 + mt) * 64 + lane], b0, acc[mt], 0, 0, 0);
#pragma unroll
    for (int mt = 0; mt < 8; ++mt)
        acc[mt] = __builtin_amdgcn_mfma_f32_16x16x32_bf16(
            Ap[(1 * 8 + mt) * 64 + lane], b1, acc[mt], 0, 0, 0);

    // epilogue: z = acc + G2 ; a = sum tanh(z)*W2 ; reduce ; p = exp(a+b2)
    float part = 0.f;
#pragma unroll
    for (int mt = 0; mt < 8; ++mt) {
        const bf16x8 gr = g2r[mt >> 1];
        const int h4 = (mt & 1) * 4;
        const float4 w2v = *reinterpret_cast<const float4*>(W2 + mt * 16 + g * 4);
        const float z0 = acc[mt][0] + bf2f((ushort)gr[h4 + 0]);
        const float z1 = acc[mt][1] + bf2f((ushort)gr[h4 + 1]);
        const float z2 = acc[mt][2] + bf2f((ushort)gr[h4 + 2]);
        const float z3 = acc[mt][3] + bf2f((ushort)gr[h4 + 3]);
        part = fmaf(tanh_fast(z0), w2v.x, part);
        part = fmaf(tanh_fast(z1), w2v.y, part);
        part = fmaf(tanh_fast(z2), w2v.z, part);
        part = fmaf(tanh_fast(z3), w2v.w, part);
    }
    part += __shfl_xor(part, 16, 64);
    part += __shfl_xor(part, 32, 64);
    if (lane < 16) csr_p[pos] = __expf(part + b2[0]);
}

// ---------------------------------------------------------------------------
// K3: per-node gather-aggregate, wave-per-node; 4 edge-slots x 16 col-lanes,
// inner loop unrolled x2 (8 Hb-row gathers in flight); bf16 out.
// ---------------------------------------------------------------------------
__global__ __launch_bounds__(256) void k_agg(
    const int* __restrict__ rowptr, const float* __restrict__ csr_p,
    const int2* __restrict__ edrec, const ushort* __restrict__ Hb,
    ushort* __restrict__ AGGb)
{
    const int tid = threadIdx.x;
    const int wave = tid >> 6, lane = tid & 63;
    const int slot = lane >> 4, tc = lane & 15;
    const int n = blockIdx.x * 4 + wave;
    const int beg = rowptr[n], end = rowptr[n + 1];

    float v[8];
#pragma unroll
    for (int i = 0; i < 8; ++i) v[i] = 0.f;
    float sp = 0.f;

    int j = beg + slot;
    for (; j + 4 < end; j += 8) {
        const float p0 = csr_p[j];
        const int d0 = edrec[j].y & 0xffff;
        const float p1 = csr_p[j + 4];
        const int d1 = edrec[j + 4].y & 0xffff;
        const bf16x8 h0 = *reinterpret_cast<const bf16x8*>(Hb + (size_t)d0 * 128 + tc * 8);
        const bf16x8 h1 = *reinterpret_cast<const bf16x8*>(Hb + (size_t)d1 * 128 + tc * 8);
#pragma unroll
        for (int i = 0; i < 8; ++i) {
            v[i] = fmaf(p0, bf2f((ushort)h0[i]), v[i]);
            v[i] = fmaf(p1, bf2f((ushort)h1[i]), v[i]);
        }
        sp += p0 + p1;
    }
    for (; j < end; j += 4) {
        const float p = csr_p[j];
        const int d = edrec[j].y & 0xffff;
        const bf16x8 hv = *reinterpret_cast<const bf16x8*>(Hb + (size_t)d * 128 + tc * 8);
#pragma unroll
        for (int i = 0; i < 8; ++i) v[i] = fmaf(p, bf2f((ushort)hv[i]), v[i]);
        sp += p;
    }
#pragma unroll
    for (int m = 16; m <= 32; m <<= 1) {
#pragma unroll
        for (int i = 0; i < 8; ++i) v[i] += __shfl_xor(v[i], m, 64);
        sp += __shfl_xor(sp, m, 64);
    }
    if (lane < 16) {
        const float inv = (end > beg) ? 1.f / sp : 0.f;
        bf16x8 o;
#pragma unroll
        for (int i = 0; i < 8; ++i) o[i] = (short)f2bf(v[i] * inv);
        *reinterpret_cast<bf16x8*>(AGGb + (size_t)n * 128 + tc * 8) = o;
    }
}

// ---------------------------------------------------------------------------
// K4: o = agg @ W_out + b_out (MFMA) ; LayerNorm ; ReLU
// ---------------------------------------------------------------------------
__global__ __launch_bounds__(256) void k_out_ln(
    const ushort* __restrict__ AGGb, const ushort* __restrict__ packO,
    const float* __restrict__ b, const float* __restrict__ gamma,
    const float* __restrict__ beta, float* __restrict__ OUT)
{
    const int tid = threadIdx.x;
    const int wave = tid >> 6, lane = tid & 63;
    const int r = lane & 15, g = lane >> 4;
    const int nbase = blockIdx.x * 64 + wave * 16;
    const ushort* rowA = AGGb + (size_t)(nbase + r) * 128 + g * 8;
    const bf16x8* Bp = reinterpret_cast<const bf16x8*>(packO);

    f32x4 acc[8];
#pragma unroll
    for (int nt = 0; nt < 8; ++nt) {
        const float bv = b[nt * 16 + r];
        acc[nt] = (f32x4){bv, bv, bv, bv};
    }
#pragma unroll
    for (int k0 = 0; k0 < 4; ++k0) {
        const bf16x8 a = *reinterpret_cast<const bf16x8*>(rowA + k0 * 32);
#pragma unroll
        for (int nt = 0; nt < 8; ++nt)
            acc[nt] = __builtin_amdgcn_mfma_f32_16x16x32_bf16(
                a, Bp[(k0 * 8 + nt) * 64 + lane], acc[nt], 0, 0, 0);
    }

    float s1[4] = {0.f, 0.f, 0.f, 0.f};
    float s2[4] = {0.f, 0.f, 0.f, 0.f};
#pragma unroll
    for (int nt = 0; nt < 8; ++nt) {
#pragma unroll
        for (int q = 0; q < 4; ++q) {
            const float z = acc[nt][q];
            s1[q] += z;
            s2[q] = fmaf(z, z, s2[q]);
        }
    }
#pragma unroll
    for (int m = 1; m <= 8; m <<= 1) {
#pragma unroll
        for (int q = 0; q < 4; ++q) {
            s1[q] += __shfl_xor(s1[q], m, 64);
            s2[q] += __shfl_xor(s2[q], m, 64);
        }
    }
    float mu[4], rr[4];
#pragma unroll
    for (int q = 0; q < 4; ++q) {
        mu[q] = s1[q] * (1.f / 128.f);
        const float var = s2[q] * (1.f / 128.f) - mu[q] * mu[q];
        rr[q] = rsqrtf(var + 1e-5f);
    }
#pragma unroll
    for (int nt = 0; nt < 8; ++nt) {
        const int col = nt * 16 + r;
        const float ga = gamma[col], be = beta[col];
#pragma unroll
        for (int q = 0; q < 4; ++q) {
            const float o = (acc[nt][q] - mu[q]) * rr[q] * ga + be;
            OUT[(size_t)(nbase + g * 4 + q) * 128 + col] = o > 0.f ? o : 0.f;
        }
    }
}

// ---------------------------------------------------------------------------
extern "C" void kernel_launch(void* const* d_in, const int* in_sizes, int n_in,
                              void* d_out, int out_size, void* d_ws, size_t ws_size,
                              hipStream_t stream)
{
    const float* node_features = (const float*)d_in[0];
    const int*   edge_index    = (const int*)d_in[1];
    const float* edge_features = (const float*)d_in[2];
    const float* W_node  = (const float*)d_in[3];
    const float* b_node  = (const float*)d_in[4];
    const float* W_edge  = (const float*)d_in[5];
    const float* b_edge  = (const float*)d_in[6];
    const float* W_att1  = (const float*)d_in[7];
    const float* b_att1  = (const float*)d_in[8];
    const float* W_att2  = (const float*)d_in[9];
    const float* b_att2  = (const float*)d_in[10];
    const float* W_out   = (const float*)d_in[11];
    const float* b_out   = (const float*)d_in[12];
    const float* ln_gamma = (const float*)d_in[13];
    const float* ln_beta  = (const float*)d_in[14];
    float* out = (float*)d_out;

    // workspace layout (byte offsets, 16B-aligned)
    char* ws = (char*)d_ws;
    ushort* hb      = (ushort*)(ws);                   // 10,240,000 B
    ushort* G1      = (ushort*)(ws + 10240000);        // 10,240,000 B
    ushort* G2      = (ushort*)(ws + 20480000);        // 10,240,000 B
    ushort* aggb    = (ushort*)(ws + 30720000);        // 10,240,000 B
    float*  csr_p   = (float*)(ws + 40960000);         //  2,560,000 B
    int2*   edrec   = (int2*)(ws + 43520000);          //  5,120,000 B
    int*    rowptr  = (int*)(ws + 48640000);           //    160,004 B
    int*    cnt     = (int*)(ws + 48800016);           //    160,000 B
    int*    cursor  = (int*)(ws + 48960016);           //    160,000 B (contiguous after cnt)
    float*  Wc      = (float*)(ws + 49120016);         //     32,768 B
    float*  b_eff   = (float*)(ws + 49152784);         //        512 B
    ushort* packB   = (ushort*)(ws + 49153296);        //     65,536 B
    ushort* packA   = (ushort*)(ws + 49218832);        //     16,384 B
    ushort* packN   = (ushort*)(ws + 49235216);        //     32,768 B
    ushort* packO   = (ushort*)(ws + 49267984);        //     32,768 B

    const int* srcI = edge_index;
    const int* dstI = edge_index + N_EDGES;

    // zero histogram + fill cursors (contiguous)
    hipMemsetAsync(cnt, 0, 320000, stream);

    // A: wcomb (33) + hist (2500)
    k_A<<<2533, 256, 0, stream>>>(W_edge, W_att1, b_att1, b_edge, Wc, b_eff,
                                  srcI, cnt);
    // B: pack (72x1024) + scan (1)
    k_B<<<73, 1024, 0, stream>>>(W_att1, Wc, W_node, W_out,
                                 packB, packA, packN, packO, cnt, rowptr);
    // C: node_gemm (625) + fill (2500)
    k_C<<<3125, 256, 0, stream>>>(node_features, packN, b_node, hb,
                                  srcI, dstI, rowptr, cursor, edrec);
    k_node_g12<<<N_NODES / 64, 256, 0, stream>>>(hb, packB, b_eff, G1, G2);
    k_edge_att_v10<<<N_EDGES / 64, 256, 0, stream>>>(edrec, edge_features,
                                                     G1, G2, packA, W_att2, b_att2,
                                                     csr_p);
    k_agg<<<N_NODES / 4, 256, 0, stream>>>(rowptr, csr_p, edrec, hb, aggb);
    k_out_ln<<<N_NODES / 64, 256, 0, stream>>>(aggb, packO, b_out, ln_gamma, ln_beta, out);
}

// Round 20
// 207.571 us; speedup vs baseline: 1.3584x; 1.1140x over previous
//
#include <hip/hip_runtime.h>
#include <math.h>

#define N_NODES 40000
#define N_EDGES 640000
#define IN_DIM 128
#define EDGE_DIM 64
#define HID 128

typedef __attribute__((ext_vector_type(8))) short bf16x8;
typedef __attribute__((ext_vector_type(4))) float f32x4;

__device__ __forceinline__ ushort f2bf(float f) {
    unsigned int x = __float_as_uint(f);
    x += 0x7fffu + ((x >> 16) & 1u);
    return (ushort)(x >> 16);
}
__device__ __forceinline__ float bf2f(ushort u) {
    return __uint_as_float(((unsigned int)u) << 16);
}
// tanh(x) = 1 - 2/(e^{2x}+1); e^{2x}=inf -> 1, e^{2x}=0 -> -1 (no NaN)
__device__ __forceinline__ float tanh_fast(float x) {
    return 1.f - __fdividef(2.f, __expf(2.f * x) + 1.f);
}

// ---------------------------------------------------------------------------
// Launch A (256 thr): blocks 0..32 = wcomb ; blocks 33..2532 = hist
// ---------------------------------------------------------------------------
__global__ __launch_bounds__(256) void k_A(
    const float* __restrict__ W_edge, const float* __restrict__ W1,
    const float* __restrict__ b_att1, const float* __restrict__ b_edge,
    float* __restrict__ Wc, float* __restrict__ b_eff,
    const int* __restrict__ srcI, int* __restrict__ cnt)
{
    const int bid = blockIdx.x;
    if (bid < 33) {
        const float* W1he = W1 + 256 * 128;
        if (bid == 32) {
            const int n = threadIdx.x;
            if (n < 128) {
                float s = b_att1[n];
                for (int k = 0; k < 128; ++k) s = fmaf(b_edge[k], W1he[k * 128 + n], s);
                b_eff[n] = s;
            }
            return;
        }
        const int idx = bid * 256 + threadIdx.x;
        const int row = idx >> 7, n = idx & 127;
        float s = 0.f;
        for (int k = 0; k < 128; ++k) s = fmaf(W_edge[row * 128 + k], W1he[k * 128 + n], s);
        Wc[idx] = s;
    } else {
        const int e = (bid - 33) * 256 + threadIdx.x;
        atomicAdd(&cnt[srcI[e]], 1);
    }
}

// ---------------------------------------------------------------------------
// Launch B (1024 thr): blocks 0..71 = pack ; block 72 = scan
// ---------------------------------------------------------------------------
__global__ __launch_bounds__(1024) void k_B(
    const float* __restrict__ W1, const float* __restrict__ Wc,
    const float* __restrict__ Wn, const float* __restrict__ Wo,
    ushort* __restrict__ packB, ushort* __restrict__ packA,
    ushort* __restrict__ packN, ushort* __restrict__ packO,
    const int* __restrict__ cnt, int* __restrict__ rowptr)
{
    const int bid = blockIdx.x;
    if (bid < 72) {
        const int idx = bid * 1024 + threadIdx.x;   // 0..73727
        if (idx < 32768) {
            const int j = idx & 7, lane = (idx >> 3) & 63, nt = (idx >> 9) & 7, k0 = idx >> 12;
            const int k = k0 * 32 + (lane >> 4) * 8 + j;
            const int n = nt * 16 + (lane & 15);
            packB[idx] = f2bf(W1[k * 128 + n]);
        } else if (idx < 40960) {
            const int i2 = idx - 32768;
            const int j = i2 & 7, lane = (i2 >> 3) & 63, mt = (i2 >> 9) & 7, k0 = i2 >> 12;
            const int k = k0 * 32 + (lane >> 4) * 8 + j;
            const int row = mt * 16 + (lane & 15);
            packA[i2] = f2bf(Wc[k * 128 + row]);
        } else if (idx < 57344) {
            const int i3 = idx - 40960;
            const int j = i3 & 7, lane = (i3 >> 3) & 63, nt = (i3 >> 9) & 7, k0 = i3 >> 12;
            const int k = k0 * 32 + (lane >> 4) * 8 + j;
            const int n = nt * 16 + (lane & 15);
            packN[i3] = f2bf(Wn[k * 128 + n]);
        } else {
            const int i4 = idx - 57344;
            const int j = i4 & 7, lane = (i4 >> 3) & 63, nt = (i4 >> 9) & 7, k0 = i4 >> 12;
            const int k = k0 * 32 + (lane >> 4) * 8 + j;
            const int n = nt * 16 + (lane & 15);
            packO[i4] = f2bf(Wo[k * 128 + n]);
        }
        return;
    }
    // --- scan (single block, 4 elems/thread) ---
    __shared__ int wsum[16];
    __shared__ int carry;
    const int tid = threadIdx.x, lane = tid & 63, wid = tid >> 6;
    if (tid == 0) { carry = 0; rowptr[0] = 0; }
    __syncthreads();
    for (int base = 0; base < N_NODES; base += 4096) {
        const int i = base + tid * 4;
        int4 c = {0, 0, 0, 0};
        if (i < N_NODES) c = *reinterpret_cast<const int4*>(cnt + i);
        const int tsum = c.x + c.y + c.z + c.w;
        int v = tsum;
#pragma unroll
        for (int d = 1; d < 64; d <<= 1) {
            const int t = __shfl_up(v, d, 64);
            if (lane >= d) v += t;
        }
        if (lane == 63) wsum[wid] = v;
        __syncthreads();
        if (wid == 0 && lane < 16) {
            int w = wsum[lane];
#pragma unroll
            for (int d = 1; d < 16; d <<= 1) {
                const int t = __shfl_up(w, d, 16);
                if ((lane & 15) >= d) w += t;
            }
            wsum[lane] = w;
        }
        __syncthreads();
        const int off = (wid == 0) ? 0 : wsum[wid - 1];
        const int excl = carry + off + v - tsum;
        if (i < N_NODES) {
            rowptr[i + 1] = excl + c.x;
            rowptr[i + 2] = excl + c.x + c.y;
            rowptr[i + 3] = excl + c.x + c.y + c.z;
            rowptr[i + 4] = excl + tsum;
        }
        const int total = wsum[15];
        __syncthreads();
        if (tid == 0) carry += total;
        __syncthreads();
    }
}

// ---------------------------------------------------------------------------
// Launch C (256 thr): blocks 0..624 = node_hg (node_gemm + G1/G2 fused via
// per-wave LDS transpose) ; blocks 625..3124 = fill.
// node_hg: h = X@Wn + b (MFMA, C-layout) -> LDS [16][144] bf16 (pad keeps
// b128 reads 16B-aligned, ~4-way banks) -> A-frags -> G1/G2 GEMMs ->
// permuted global stores. Same-wave LDS produce/consume: no __syncthreads.
// ---------------------------------------------------------------------------
__global__ __launch_bounds__(256) void k_C(
    const float* __restrict__ X, const ushort* __restrict__ packN,
    const ushort* __restrict__ packB, const float* __restrict__ b,
    const float* __restrict__ b_eff, ushort* __restrict__ Hb,
    ushort* __restrict__ G1, ushort* __restrict__ G2,
    const int* __restrict__ srcI, const int* __restrict__ dstI,
    const int* __restrict__ rowptr, int* __restrict__ cursor,
    int2* __restrict__ edrec)
{
    const int bid = blockIdx.x;
    if (bid >= 625) {
        // --- fill: edrec[pos] = (e, si<<16|di), single 8B scattered store ---
        const int e = (bid - 625) * 256 + threadIdx.x;
        const int s = srcI[e];
        const int pos = rowptr[s] + atomicAdd(&cursor[s], 1);
        int2 rec;
        rec.x = e;
        rec.y = (s << 16) | dstI[e];
        edrec[pos] = rec;
        return;
    }
    // --- node_hg ---
    __shared__ ushort hs[4][16][144];   // 18 KB
    const int tid = threadIdx.x;
    const int wave = tid >> 6, lane = tid & 63;
    const int r = lane & 15, g = lane >> 4;
    const int nbase = bid * 64 + wave * 16;
    const float* rowX = X + (size_t)(nbase + r) * 128 + g * 8;
    const bf16x8* BpN = reinterpret_cast<const bf16x8*>(packN);
    const bf16x8* BpB = reinterpret_cast<const bf16x8*>(packB);

    // phase 1: h = X @ W_node + b
    f32x4 acc[8];
#pragma unroll
    for (int nt = 0; nt < 8; ++nt) {
        const float bv = b[nt * 16 + r];
        acc[nt] = (f32x4){bv, bv, bv, bv};
    }
#pragma unroll
    for (int k0 = 0; k0 < 4; ++k0) {
        const float4 u0 = *reinterpret_cast<const float4*>(rowX + k0 * 32);
        const float4 u1 = *reinterpret_cast<const float4*>(rowX + k0 * 32 + 4);
        bf16x8 a;
        a[0] = (short)f2bf(u0.x); a[1] = (short)f2bf(u0.y);
        a[2] = (short)f2bf(u0.z); a[3] = (short)f2bf(u0.w);
        a[4] = (short)f2bf(u1.x); a[5] = (short)f2bf(u1.y);
        a[6] = (short)f2bf(u1.z); a[7] = (short)f2bf(u1.w);
#pragma unroll
        for (int nt = 0; nt < 8; ++nt)
            acc[nt] = __builtin_amdgcn_mfma_f32_16x16x32_bf16(
                a, BpN[(k0 * 8 + nt) * 64 + lane], acc[nt], 0, 0, 0);
    }
    // write h: global Hb + LDS tile (C-layout scatter)
#pragma unroll
    for (int nt = 0; nt < 8; ++nt) {
#pragma unroll
        for (int q = 0; q < 4; ++q) {
            const ushort bv = f2bf(acc[nt][q]);
            Hb[(size_t)(nbase + g * 4 + q) * 128 + nt * 16 + r] = bv;
            hs[wave][g * 4 + q][nt * 16 + r] = bv;
        }
    }

    // phase 2: A-frags from LDS (same wave wrote them; lgkmcnt orders)
    bf16x8 afr[4];
#pragma unroll
    for (int k0 = 0; k0 < 4; ++k0)
        afr[k0] = *reinterpret_cast<const bf16x8*>(&hs[wave][r][k0 * 32 + g * 8]);

    const int coff = (r >> 2) * 32 + (r & 3);

    // G1 = h @ W1a + b_eff (permuted store)
#pragma unroll
    for (int nt = 0; nt < 8; ++nt) acc[nt] = (f32x4){0.f, 0.f, 0.f, 0.f};
#pragma unroll
    for (int k0 = 0; k0 < 4; ++k0) {
#pragma unroll
        for (int nt = 0; nt < 8; ++nt)
            acc[nt] = __builtin_amdgcn_mfma_f32_16x16x32_bf16(
                afr[k0], BpB[(k0 * 8 + nt) * 64 + lane], acc[nt], 0, 0, 0);
    }
#pragma unroll
    for (int nt = 0; nt < 8; ++nt) {
        const float bv = b_eff[nt * 16 + r];
#pragma unroll
        for (int q = 0; q < 4; ++q)
            G1[(size_t)(nbase + g * 4 + q) * 128 + coff + nt * 4] = f2bf(acc[nt][q] + bv);
    }

    // G2 = h @ W1b (permuted store)
#pragma unroll
    for (int nt = 0; nt < 8; ++nt) acc[nt] = (f32x4){0.f, 0.f, 0.f, 0.f};
#pragma unroll
    for (int k0 = 0; k0 < 4; ++k0) {
#pragma unroll
        for (int nt = 0; nt < 8; ++nt)
            acc[nt] = __builtin_amdgcn_mfma_f32_16x16x32_bf16(
                afr[k0], BpB[((k0 + 4) * 8 + nt) * 64 + lane], acc[nt], 0, 0, 0);
    }
#pragma unroll
    for (int nt = 0; nt < 8; ++nt) {
#pragma unroll
        for (int q = 0; q < 4; ++q)
            G2[(size_t)(nbase + g * 4 + q) * 128 + coff + nt * 4] = f2bf(acc[nt][q]);
    }
}

// ---------------------------------------------------------------------------
// K2 v10: CSR-ordered edge attention. G1 (L1-hot) in acc init; G2 (random)
// hoisted raw, folded at tanh epilogue.
// ---------------------------------------------------------------------------
__global__ __launch_bounds__(256) void k_edge_att_v10(
    const int2* __restrict__ edrec, const float* __restrict__ EF,
    const ushort* __restrict__ G1, const ushort* __restrict__ G2,
    const ushort* __restrict__ packA,
    const float* __restrict__ W2, const float* __restrict__ b2,
    float* __restrict__ csr_p)
{
    const int tid = threadIdx.x;
    const int wave = tid >> 6, lane = tid & 63;
    const int r = lane & 15, g = lane >> 4;
    const int pbase = blockIdx.x * 64 + wave * 16;
    const int pos = pbase + r;
    const int2 rec = edrec[pos];
    const int e = rec.x;
    const int di = rec.y & 0xffff;
    const int si = ((unsigned)rec.y) >> 16;

    const ushort* g2base = G2 + (size_t)di * 128 + g * 32;
    bf16x8 g2r[4];
#pragma unroll
    for (int m2 = 0; m2 < 4; ++m2)
        g2r[m2] = *reinterpret_cast<const bf16x8*>(g2base + m2 * 8);

    const ushort* g1base = G1 + (size_t)si * 128 + g * 32;
    f32x4 acc[8];
#pragma unroll
    for (int m2 = 0; m2 < 4; ++m2) {
        const bf16x8 a = *reinterpret_cast<const bf16x8*>(g1base + m2 * 8);
#pragma unroll
        for (int q = 0; q < 4; ++q) {
            acc[2 * m2][q]     = bf2f((ushort)a[q]);
            acc[2 * m2 + 1][q] = bf2f((ushort)a[4 + q]);
        }
    }

    const float* rowE = EF + (size_t)e * 64 + g * 8;
    bf16x8 b0, b1;
    {
        const float4 u0 = *reinterpret_cast<const float4*>(rowE);
        const float4 u1 = *reinterpret_cast<const float4*>(rowE + 4);
        b0[0] = (short)f2bf(u0.x); b0[1] = (short)f2bf(u0.y);
        b0[2] = (short)f2bf(u0.z); b0[3] = (short)f2bf(u0.w);
        b0[4] = (short)f2bf(u1.x); b0[5] = (short)f2bf(u1.y);
        b0[6] = (short)f2bf(u1.z); b0[7] = (short)f2bf(u1.w);
        const float4 v0 = *reinterpret_cast<const float4*>(rowE + 32);
        const float4 v1 = *reinterpret_cast<const float4*>(rowE + 36);
        b1[0] = (short)f2bf(v0.x); b1[1] = (short)f2bf(v0.y);
        b1[2] = (short)f2bf(v0.z); b1[3] = (short)f2bf(v0.w);
        b1[4] = (short)f2bf(v1.x); b1[5] = (short)f2bf(v1.y);
        b1[6] = (short)f2bf(v1.z); b1[7] = (short)f2bf(v1.w);
    }

    const bf16x8* Ap = reinterpret_cast<const bf16x8*>(packA);
#pragma unroll
    for (int mt = 0; mt < 8; ++mt)
        acc[mt] = __builtin_amdgcn_mfma_f32_16x16x32_bf16(
            Ap[(0 * 8 + mt) * 64 + lane], b0, acc[mt], 0, 0, 0);
#pragma unroll
    for (int mt = 0; mt < 8; ++mt)
        acc[mt] = __builtin_amdgcn_mfma_f32_16x16x32_bf16(
            Ap[(1 * 8 + mt) * 64 + lane], b1, acc[mt], 0, 0, 0);

    float part = 0.f;
#pragma unroll
    for (int mt = 0; mt < 8; ++mt) {
        const bf16x8 gr = g2r[mt >> 1];
        const int h4 = (mt & 1) * 4;
        const float4 w2v = *reinterpret_cast<const float4*>(W2 + mt * 16 + g * 4);
        const float z0 = acc[mt][0] + bf2f((ushort)gr[h4 + 0]);
        const float z1 = acc[mt][1] + bf2f((ushort)gr[h4 + 1]);
        const float z2 = acc[mt][2] + bf2f((ushort)gr[h4 + 2]);
        const float z3 = acc[mt][3] + bf2f((ushort)gr[h4 + 3]);
        part = fmaf(tanh_fast(z0), w2v.x, part);
        part = fmaf(tanh_fast(z1), w2v.y, part);
        part = fmaf(tanh_fast(z2), w2v.z, part);
        part = fmaf(tanh_fast(z3), w2v.w, part);
    }
    part += __shfl_xor(part, 16, 64);
    part += __shfl_xor(part, 32, 64);
    if (lane < 16) csr_p[pos] = __expf(part + b2[0]);
}

// ---------------------------------------------------------------------------
// K3: per-node gather-aggregate, wave-per-node; x2 unrolled; bf16 out.
// ---------------------------------------------------------------------------
__global__ __launch_bounds__(256) void k_agg(
    const int* __restrict__ rowptr, const float* __restrict__ csr_p,
    const int2* __restrict__ edrec, const ushort* __restrict__ Hb,
    ushort* __restrict__ AGGb)
{
    const int tid = threadIdx.x;
    const int wave = tid >> 6, lane = tid & 63;
    const int slot = lane >> 4, tc = lane & 15;
    const int n = blockIdx.x * 4 + wave;
    const int beg = rowptr[n], end = rowptr[n + 1];

    float v[8];
#pragma unroll
    for (int i = 0; i < 8; ++i) v[i] = 0.f;
    float sp = 0.f;

    int j = beg + slot;
    for (; j + 4 < end; j += 8) {
        const float p0 = csr_p[j];
        const int d0 = edrec[j].y & 0xffff;
        const float p1 = csr_p[j + 4];
        const int d1 = edrec[j + 4].y & 0xffff;
        const bf16x8 h0 = *reinterpret_cast<const bf16x8*>(Hb + (size_t)d0 * 128 + tc * 8);
        const bf16x8 h1 = *reinterpret_cast<const bf16x8*>(Hb + (size_t)d1 * 128 + tc * 8);
#pragma unroll
        for (int i = 0; i < 8; ++i) {
            v[i] = fmaf(p0, bf2f((ushort)h0[i]), v[i]);
            v[i] = fmaf(p1, bf2f((ushort)h1[i]), v[i]);
        }
        sp += p0 + p1;
    }
    for (; j < end; j += 4) {
        const float p = csr_p[j];
        const int d = edrec[j].y & 0xffff;
        const bf16x8 hv = *reinterpret_cast<const bf16x8*>(Hb + (size_t)d * 128 + tc * 8);
#pragma unroll
        for (int i = 0; i < 8; ++i) v[i] = fmaf(p, bf2f((ushort)hv[i]), v[i]);
        sp += p;
    }
#pragma unroll
    for (int m = 16; m <= 32; m <<= 1) {
#pragma unroll
        for (int i = 0; i < 8; ++i) v[i] += __shfl_xor(v[i], m, 64);
        sp += __shfl_xor(sp, m, 64);
    }
    if (lane < 16) {
        const float inv = (end > beg) ? 1.f / sp : 0.f;
        bf16x8 o;
#pragma unroll
        for (int i = 0; i < 8; ++i) o[i] = (short)f2bf(v[i] * inv);
        *reinterpret_cast<bf16x8*>(AGGb + (size_t)n * 128 + tc * 8) = o;
    }
}

// ---------------------------------------------------------------------------
// K4: o = agg @ W_out + b_out (MFMA) ; LayerNorm ; ReLU
// ---------------------------------------------------------------------------
__global__ __launch_bounds__(256) void k_out_ln(
    const ushort* __restrict__ AGGb, const ushort* __restrict__ packO,
    const float* __restrict__ b, const float* __restrict__ gamma,
    const float* __restrict__ beta, float* __restrict__ OUT)
{
    const int tid = threadIdx.x;
    const int wave = tid >> 6, lane = tid & 63;
    const int r = lane & 15, g = lane >> 4;
    const int nbase = blockIdx.x * 64 + wave * 16;
    const ushort* rowA = AGGb + (size_t)(nbase + r) * 128 + g * 8;
    const bf16x8* Bp = reinterpret_cast<const bf16x8*>(packO);

    f32x4 acc[8];
#pragma unroll
    for (int nt = 0; nt < 8; ++nt) {
        const float bv = b[nt * 16 + r];
        acc[nt] = (f32x4){bv, bv, bv, bv};
    }
#pragma unroll
    for (int k0 = 0; k0 < 4; ++k0) {
        const bf16x8 a = *reinterpret_cast<const bf16x8*>(rowA + k0 * 32);
#pragma unroll
        for (int nt = 0; nt < 8; ++nt)
            acc[nt] = __builtin_amdgcn_mfma_f32_16x16x32_bf16(
                a, Bp[(k0 * 8 + nt) * 64 + lane], acc[nt], 0, 0, 0);
    }

    float s1[4] = {0.f, 0.f, 0.f, 0.f};
    float s2[4] = {0.f, 0.f, 0.f, 0.f};
#pragma unroll
    for (int nt = 0; nt < 8; ++nt) {
#pragma unroll
        for (int q = 0; q < 4; ++q) {
            const float z = acc[nt][q];
            s1[q] += z;
            s2[q] = fmaf(z, z, s2[q]);
        }
    }
#pragma unroll
    for (int m = 1; m <= 8; m <<= 1) {
#pragma unroll
        for (int q = 0; q < 4; ++q) {
            s1[q] += __shfl_xor(s1[q], m, 64);
            s2[q] += __shfl_xor(s2[q], m, 64);
        }
    }
    float mu[4], rr[4];
#pragma unroll
    for (int q = 0; q < 4; ++q) {
        mu[q] = s1[q] * (1.f / 128.f);
        const float var = s2[q] * (1.f / 128.f) - mu[q] * mu[q];
        rr[q] = rsqrtf(var + 1e-5f);
    }
#pragma unroll
    for (int nt = 0; nt < 8; ++nt) {
        const int col = nt * 16 + r;
        const float ga = gamma[col], be = beta[col];
#pragma unroll
        for (int q = 0; q < 4; ++q) {
            const float o = (acc[nt][q] - mu[q]) * rr[q] * ga + be;
            OUT[(size_t)(nbase + g * 4 + q) * 128 + col] = o > 0.f ? o : 0.f;
        }
    }
}

// ---------------------------------------------------------------------------
extern "C" void kernel_launch(void* const* d_in, const int* in_sizes, int n_in,
                              void* d_out, int out_size, void* d_ws, size_t ws_size,
                              hipStream_t stream)
{
    const float* node_features = (const float*)d_in[0];
    const int*   edge_index    = (const int*)d_in[1];
    const float* edge_features = (const float*)d_in[2];
    const float* W_node  = (const float*)d_in[3];
    const float* b_node  = (const float*)d_in[4];
    const float* W_edge  = (const float*)d_in[5];
    const float* b_edge  = (const float*)d_in[6];
    const float* W_att1  = (const float*)d_in[7];
    const float* b_att1  = (const float*)d_in[8];
    const float* W_att2  = (const float*)d_in[9];
    const float* b_att2  = (const float*)d_in[10];
    const float* W_out   = (const float*)d_in[11];
    const float* b_out   = (const float*)d_in[12];
    const float* ln_gamma = (const float*)d_in[13];
    const float* ln_beta  = (const float*)d_in[14];
    float* out = (float*)d_out;

    // workspace layout (byte offsets, 16B-aligned)
    char* ws = (char*)d_ws;
    ushort* hb      = (ushort*)(ws);                   // 10,240,000 B
    ushort* G1      = (ushort*)(ws + 10240000);        // 10,240,000 B
    ushort* G2      = (ushort*)(ws + 20480000);        // 10,240,000 B
    ushort* aggb    = (ushort*)(ws + 30720000);        // 10,240,000 B
    float*  csr_p   = (float*)(ws + 40960000);         //  2,560,000 B
    int2*   edrec   = (int2*)(ws + 43520000);          //  5,120,000 B
    int*    rowptr  = (int*)(ws + 48640000);           //    160,004 B
    int*    cnt     = (int*)(ws + 48800016);           //    160,000 B
    int*    cursor  = (int*)(ws + 48960016);           //    160,000 B (contiguous after cnt)
    float*  Wc      = (float*)(ws + 49120016);         //     32,768 B
    float*  b_eff   = (float*)(ws + 49152784);         //        512 B
    ushort* packB   = (ushort*)(ws + 49153296);        //     65,536 B
    ushort* packA   = (ushort*)(ws + 49218832);        //     16,384 B
    ushort* packN   = (ushort*)(ws + 49235216);        //     32,768 B
    ushort* packO   = (ushort*)(ws + 49267984);        //     32,768 B

    const int* srcI = edge_index;
    const int* dstI = edge_index + N_EDGES;

    // zero histogram + fill cursors (contiguous)
    hipMemsetAsync(cnt, 0, 320000, stream);

    // A: wcomb (33) + hist (2500)
    k_A<<<2533, 256, 0, stream>>>(W_edge, W_att1, b_att1, b_edge, Wc, b_eff,
                                  srcI, cnt);
    // B: pack (72x1024) + scan (1)
    k_B<<<73, 1024, 0, stream>>>(W_att1, Wc, W_node, W_out,
                                 packB, packA, packN, packO, cnt, rowptr);
    // C: node_hg (625: node_gemm + G1/G2 fused) + fill (2500)
    k_C<<<3125, 256, 0, stream>>>(node_features, packN, packB, b_node, b_eff,
                                  hb, G1, G2, srcI, dstI, rowptr, cursor, edrec);
    k_edge_att_v10<<<N_EDGES / 64, 256, 0, stream>>>(edrec, edge_features,
                                                     G1, G2, packA, W_att2, b_att2,
                                                     csr_p);
    k_agg<<<N_NODES / 4, 256, 0, stream>>>(rowptr, csr_p, edrec, hb, aggb);
    k_out_ln<<<N_NODES / 64, 256, 0, stream>>>(aggb, packO, b_out, ln_gamma, ln_beta, out);
}